// Round 1
// baseline (643.966 us; speedup 1.0000x reference)
//
#include <hip/hip_runtime.h>

// B=16, L1=L2=1024, H=768
// P = relu([x1;x2] @ W^T + b); S = P1·P2^T masked; softmax; att = alpha·x2;
// out = [x1, att, x1*att, x1-att]
//
// Numerics identical to the previous passing version (hi/lo split-bf16 3-pass
// MFMA for proj+scores, order hh,hl,lh per 32-wide K-step; single-pass bf16 att).
//
// This revision: k_proj/k_scores moved from the 128² 2-barrier (m97) structure
// to a 256²-tile, 512-thread, double-buffered schedule with 3 phases per K-step
// (one per hi/lo pass, 32 MFMA each), counted s_waitcnt vmcnt(8/4) (never a
// drain inside the loop), raw s_barrier, and s_setprio around MFMA clusters.
// XCD-chunked bijective block swizzle on k_proj/k_scores/k_att for L2 panel
// locality.
//
// d_out layout (lifetimes):
//   [0,50.3M)        Ph (proj->scores), then alpha_bf16 [0,33.5M) (softmax->att)
//   [50.3M,100.7M)   Pl
//   [100.7M,167.8M)  Xh (split->proj), then scores fp32 (scores->softmax)
//   [167.8M,169.0M)  Wh   [169.0M,170.1M) Wl   [170.1M,195.3M) x2T bf16
// d_ws: [0,50.3M) Xl (split->proj), then att fp32 (att->concat)

#define B_  16
#define L_  1024
#define H_  768
#define M1_ (B_ * L_)    // 16384
#define MT_ (2 * M1_)    // 32768

#define XB_  24576       // k_split blocks for X hi/lo
#define WB_  576         // k_split blocks for W hi/lo
#define TB_  3072        // k_split blocks for x2 transpose

using f32x4  = __attribute__((ext_vector_type(4))) float;
using bf16x8 = __attribute__((ext_vector_type(8))) __bf16;
using u16x8  = __attribute__((ext_vector_type(8))) unsigned short;
using u16x4  = __attribute__((ext_vector_type(4))) unsigned short;

__device__ inline unsigned short f2b(float f) {
  unsigned u = __builtin_bit_cast(unsigned, f);
  u += 0x7FFFu + ((u >> 16) & 1u);   // RNE; no NaN/inf in data
  return (unsigned short)(u >> 16);
}
__device__ inline float b2f(unsigned short u) {
  return __builtin_bit_cast(float, ((unsigned)u) << 16);
}

// async global->LDS, 16 B per lane; LDS dest = wave-uniform base + lane*16
__device__ inline void gld16(const void* g, void* l) {
  __builtin_amdgcn_global_load_lds(
      (__attribute__((address_space(1))) void*)g,
      (__attribute__((address_space(3))) void*)l, 16, 0, 0);
}

// Tile: [rows][32 u16] = 64 B/row, chunk (16B) swizzle: slot = chunk ^ ((row>>1)&3).
// ds_read_b128 fragment reads are then bank-balanced (max 2-way = free).
__device__ inline bf16x8 ld_frag_sw(const unsigned short* lds, int row, int quad) {
  const int sl = quad ^ ((row >> 1) & 3);
  u16x8 v = *(const u16x8*)(lds + row * 32 + sl * 8);
  return __builtin_bit_cast(bf16x8, v);
}

#define MFMA(a, b, c) __builtin_amdgcn_mfma_f32_16x16x32_bf16((a), (b), (c), 0, 0, 0)

// Stage one 256x32-u16 matrix-half (16 KB) with 8 waves: 2 gld16 per wave.
// Source chunk pre-swizzled (lsw) so linear LDS writes realize the read swizzle.
__device__ __forceinline__ void stage2(const unsigned short* __restrict__ src,
                                       unsigned short* ldsbase,
                                       int wv, int lq, int lsw,
                                       size_t row0, int k0) {
#pragma unroll
  for (int g = 0; g < 2; ++g) {
    const int rowl = wv * 32 + g * 16;
    gld16(src + (row0 + rowl + lq) * (size_t)H_ + k0 + lsw * 8,
          ldsbase + rowl * 32);
  }
}

// 256x256-tile, BK=32, hi/lo 3-pass K-loop. 8 waves (2Mx4N), per-wave 128x64.
// Phase schedule per K-step t (buffers c = compute, c^1 = stage):
//   ph0: ds_read Ah,Bh frags | issue all 8 gld16 for t+1 | bar | 32 MFMA hh |
//        vmcnt(8) [Al(t),Bl(t) landed] | bar
//   ph1: ds_read Bl frags | bar | 32 MFMA hl | bar
//   ph2: ds_read Al frags | bar | 32 MFMA lh | vmcnt(4) [Ah,Bh(t+1) landed] | bar
// Outstanding queue order is always [Ah,Ah,Bh,Bh,Al,Al,Bl,Bl] per step, so the
// counted waits are exact. Last iteration: no issues; ph0-end drains vmcnt(0).
__device__ __forceinline__ void gemm3_loop(
    const unsigned short* __restrict__ Agh, const unsigned short* __restrict__ Agl,
    const unsigned short* __restrict__ Bgh, const unsigned short* __restrict__ Bgl,
    size_t arow0, size_t brow0,
    unsigned short* SA, unsigned short* SB, f32x4 (&acc)[8][4])
{
  const int tid  = threadIdx.x;
  const int lane = tid & 63, wv = tid >> 6;
  const int wr = wv >> 2, wc = wv & 3;
  const int quad = lane >> 4, lx = lane & 15;
  const int lq  = lane >> 2;
  const int lsw = (lane & 3) ^ ((lane >> 3) & 3);
  constexpr int HB = 256 * 32;   // u16 per matrix-half buffer (16 KB)

  // prologue: tile 0 -> buf 0; queue [Ah,Ah,Bh,Bh,Al,Al,Bl,Bl]
  stage2(Agh, SA,      wv, lq, lsw, arow0, 0);
  stage2(Bgh, SB,      wv, lq, lsw, brow0, 0);
  stage2(Agl, SA + HB, wv, lq, lsw, arow0, 0);
  stage2(Bgl, SB + HB, wv, lq, lsw, brow0, 0);
  asm volatile("s_waitcnt vmcnt(4)" ::: "memory");   // Ah0,Bh0 landed
  __builtin_amdgcn_s_barrier();

  int c = 0;
  for (int t = 0; t < H_ / 32; ++t) {
    unsigned short* sAh = SA + c * (2 * HB);
    unsigned short* sAl = sAh + HB;
    unsigned short* sBh = SB + c * (2 * HB);
    unsigned short* sBl = sBh + HB;
    unsigned short* dA  = SA + (c ^ 1) * (2 * HB);
    unsigned short* dB  = SB + (c ^ 1) * (2 * HB);
    const int  k1   = t * 32 + 32;
    const bool more = (t < H_ / 32 - 1);

    // ---------------- phase 0 : hh ----------------
    bf16x8 fah[8], fbh[4];
#pragma unroll
    for (int i = 0; i < 8; ++i) fah[i] = ld_frag_sw(sAh, wr * 128 + i * 16 + lx, quad);
#pragma unroll
    for (int j = 0; j < 4; ++j) fbh[j] = ld_frag_sw(sBh, wc * 64 + j * 16 + lx, quad);
    if (more) {
      stage2(Agh, dA,      wv, lq, lsw, arow0, k1);
      stage2(Bgh, dB,      wv, lq, lsw, brow0, k1);
      stage2(Agl, dA + HB, wv, lq, lsw, arow0, k1);
      stage2(Bgl, dB + HB, wv, lq, lsw, brow0, k1);
    }
    __builtin_amdgcn_s_barrier();
    __builtin_amdgcn_s_setprio(1);
#pragma unroll
    for (int i = 0; i < 8; ++i)
#pragma unroll
      for (int j = 0; j < 4; ++j) acc[i][j] = MFMA(fah[i], fbh[j], acc[i][j]);
    __builtin_amdgcn_s_setprio(0);
    if (more) asm volatile("s_waitcnt vmcnt(8)" ::: "memory");
    else      asm volatile("s_waitcnt vmcnt(0)" ::: "memory");
    __builtin_amdgcn_s_barrier();

    // ---------------- phase 1 : hl ----------------
    bf16x8 fbl[4];
#pragma unroll
    for (int j = 0; j < 4; ++j) fbl[j] = ld_frag_sw(sBl, wc * 64 + j * 16 + lx, quad);
    __builtin_amdgcn_s_barrier();
    __builtin_amdgcn_s_setprio(1);
#pragma unroll
    for (int i = 0; i < 8; ++i)
#pragma unroll
      for (int j = 0; j < 4; ++j) acc[i][j] = MFMA(fah[i], fbl[j], acc[i][j]);
    __builtin_amdgcn_s_setprio(0);
    __builtin_amdgcn_s_barrier();

    // ---------------- phase 2 : lh ----------------
    bf16x8 fal[8];
#pragma unroll
    for (int i = 0; i < 8; ++i) fal[i] = ld_frag_sw(sAl, wr * 128 + i * 16 + lx, quad);
    __builtin_amdgcn_s_barrier();
    __builtin_amdgcn_s_setprio(1);
#pragma unroll
    for (int i = 0; i < 8; ++i)
#pragma unroll
      for (int j = 0; j < 4; ++j) acc[i][j] = MFMA(fal[i], fbh[j], acc[i][j]);
    __builtin_amdgcn_s_setprio(0);
    if (more) asm volatile("s_waitcnt vmcnt(4)" ::: "memory");
    __builtin_amdgcn_s_barrier();

    c ^= 1;
  }
}

// ---------------- K0: split X,W into hi/lo bf16; build x2T bf16 -----------------
__global__ __launch_bounds__(256) void k_split(
    const float* __restrict__ x1, const float* __restrict__ x2,
    const float* __restrict__ W,
    unsigned short* __restrict__ Xh, unsigned short* __restrict__ Xl,
    unsigned short* __restrict__ Wh, unsigned short* __restrict__ Wl,
    unsigned short* __restrict__ x2T)
{
  __shared__ unsigned short tile[64][72];
  const int tid = threadIdx.x;
  const int bx  = blockIdx.x;

  if (bx < XB_) {
    const size_t idx = (size_t)bx * 256 + tid;          // f32x4 index over [32768][768]
    const int row = (int)(idx / 192);
    const int col = ((int)(idx % 192)) * 4;
    const float* src = (row < M1_) ? (x1 + (size_t)row * H_ + col)
                                   : (x2 + (size_t)(row - M1_) * H_ + col);
    f32x4 v = *(const f32x4*)src;
    u16x4 h, l;
#pragma unroll
    for (int q = 0; q < 4; ++q) { h[q] = f2b(v[q]); l[q] = f2b(v[q] - b2f(h[q])); }
    *(u16x4*)(Xh + idx * 4) = h;
    *(u16x4*)(Xl + idx * 4) = l;
  } else if (bx < XB_ + WB_) {
    const int idx = (bx - XB_) * 256 + tid;
    f32x4 v = *(const f32x4*)(W + (size_t)idx * 4);
    u16x4 h, l;
#pragma unroll
    for (int q = 0; q < 4; ++q) { h[q] = f2b(v[q]); l[q] = f2b(v[q] - b2f(h[q])); }
    *(u16x4*)(Wh + (size_t)idx * 4) = h;
    *(u16x4*)(Wl + (size_t)idx * 4) = l;
  } else {
    const int t  = bx - (XB_ + WB_);
    const int b  = t / 192;
    const int r  = t % 192;
    const int j0 = (r / 12) * 64;
    const int d0 = (r % 12) * 64;
#pragma unroll
    for (int p = 0; p < 4; ++p) {
      const int idx = tid + p * 256;
      const int jr  = idx >> 4;
      const int dc  = (idx & 15) * 4;
      f32x4 v = *(const f32x4*)(x2 + ((size_t)(b * L_ + j0 + jr)) * H_ + d0 + dc);
#pragma unroll
      for (int q = 0; q < 4; ++q) tile[jr][dc + q] = f2b(v[q]);
    }
    __syncthreads();
#pragma unroll
    for (int p = 0; p < 2; ++p) {
      const int idx = tid + p * 256;
      const int dr  = idx >> 3;
      const int jc  = (idx & 7) * 8;
      u16x8 o;
#pragma unroll
      for (int q = 0; q < 8; ++q) o[q] = tile[jc + q][dr];
      *(u16x8*)(x2T + ((size_t)(b * H_) + d0 + dr) * L_ + j0 + jc) = o;
    }
  }
}

// ---------------- K1: P = relu(X @ W^T + b), 3-pass hi/lo, store Ph/Pl ----------
__global__ __launch_bounds__(512, 2) void k_proj(
    const unsigned short* __restrict__ Xh, const unsigned short* __restrict__ Xl,
    const unsigned short* __restrict__ Wh, const unsigned short* __restrict__ Wl,
    const float* __restrict__ bias,
    unsigned short* __restrict__ Ph, unsigned short* __restrict__ Pl)
{
  __shared__ unsigned short SA[2 * 2 * 256 * 32];   // 64 KB: [buf][hi/lo] A
  __shared__ unsigned short SB[2 * 2 * 256 * 32];   // 64 KB: [buf][hi/lo] B

  const int tid  = threadIdx.x;
  const int lane = tid & 63, wv = tid >> 6;
  const int wr = wv >> 2, wc = wv & 3;
  const int quad = lane >> 4, lx = lane & 15;

  // XCD-chunked bijective swizzle: 384 blocks, 48/XCD; within a chunk the
  // 3 N-blocks of an M-panel are consecutive -> X panel stays in that XCD's L2.
  const int lin = blockIdx.x;
  const int s   = (lin & 7) * 48 + (lin >> 3);
  const int n0  = (s % 3) * 256;
  const int m0  = (s / 3) * 256;

  f32x4 acc[8][4] = {};
  gemm3_loop(Xh, Xl, Wh, Wl, (size_t)m0, (size_t)n0, SA, SB, acc);

#pragma unroll
  for (int j = 0; j < 4; ++j) {
    const int h = n0 + wc * 64 + j * 16 + lx;
    const float bv = bias[h];
#pragma unroll
    for (int i = 0; i < 8; ++i) {
      const int mrow = m0 + wr * 128 + i * 16 + quad * 4;
#pragma unroll
      for (int r = 0; r < 4; ++r) {
        float v = acc[i][j][r] + bv;
        v = v > 0.f ? v : 0.f;
        const unsigned short hh = f2b(v);
        const unsigned short ll = f2b(v - b2f(hh));
        const size_t off = (size_t)(mrow + r) * H_ + h;
        Ph[off] = hh;
        Pl[off] = ll;
      }
    }
  }
}

// ---------------- K2: scores = P1·P2^T (3-pass), masked -------------------------
__global__ __launch_bounds__(512, 2) void k_scores(
    const unsigned short* __restrict__ Ph, const unsigned short* __restrict__ Pl,
    const int* __restrict__ x2_mask, float* __restrict__ scores)
{
  __shared__ unsigned short SA[2 * 2 * 256 * 32];
  __shared__ unsigned short SB[2 * 2 * 256 * 32];

  const int tid  = threadIdx.x;
  const int lane = tid & 63, wv = tid >> 6;
  const int wr = wv >> 2, wc = wv & 3;
  const int quad = lane >> 4, lx = lane & 15;

  // 256 blocks, 32/XCD = 2 full batches per XCD; j fastest -> i-panel L2 reuse.
  const int lin = blockIdx.x;
  const int s   = (lin & 7) * 32 + (lin >> 3);
  const int j0  = (s & 3) * 256;
  const int i0  = ((s >> 2) & 3) * 256;
  const int b   = s >> 4;

  f32x4 acc[8][4] = {};
  gemm3_loop(Ph, Pl, Ph, Pl,
             (size_t)(b * L_ + i0), (size_t)(M1_ + b * L_ + j0), SA, SB, acc);

#pragma unroll
  for (int j = 0; j < 4; ++j) {
    const int jj = j0 + wc * 64 + j * 16 + lx;
    const int mv = x2_mask[b * L_ + jj];
#pragma unroll
    for (int i = 0; i < 8; ++i) {
      const int ib = i0 + wr * 128 + i * 16 + quad * 4;
#pragma unroll
      for (int r = 0; r < 4; ++r) {
        const float v = mv ? -1e30f : acc[i][j][r];
        scores[((size_t)(b * L_) + ib + r) * L_ + jj] = v;
      }
    }
  }
}

// ---------------- K3: row softmax, fp32 in -> bf16 alpha out --------------------
__global__ __launch_bounds__(256) void k_softmax(
    const float* __restrict__ scores, unsigned short* __restrict__ alphab)
{
  const size_t row = blockIdx.x;
  const float* p = scores + row * L_;
  const int tid = threadIdx.x;

  f32x4 v = *(const f32x4*)(p + tid * 4);
  float m = fmaxf(fmaxf(v[0], v[1]), fmaxf(v[2], v[3]));
#pragma unroll
  for (int off = 32; off > 0; off >>= 1) m = fmaxf(m, __shfl_down(m, off));

  __shared__ float rmax[4];
  __shared__ float rsum[4];
  const int wid = tid >> 6, lane = tid & 63;
  if (lane == 0) rmax[wid] = m;
  __syncthreads();
  m = fmaxf(fmaxf(rmax[0], rmax[1]), fmaxf(rmax[2], rmax[3]));

  f32x4 e;
#pragma unroll
  for (int q = 0; q < 4; ++q) e[q] = __expf(v[q] - m);
  float s = e[0] + e[1] + e[2] + e[3];
#pragma unroll
  for (int off = 32; off > 0; off >>= 1) s += __shfl_down(s, off);
  if (lane == 0) rsum[wid] = s;
  __syncthreads();
  s = rsum[0] + rsum[1] + rsum[2] + rsum[3];

  const float inv = 1.0f / s;
  u16x4 o;
#pragma unroll
  for (int q = 0; q < 4; ++q) o[q] = f2b(e[q] * inv);
  *(u16x4*)(alphab + row * L_ + tid * 4) = o;
}

// ---------------- K4: att = alpha @ x2 (bf16 single-pass) -----------------------
__global__ __launch_bounds__(256) void k_att(
    const unsigned short* __restrict__ alphab, const unsigned short* __restrict__ x2T,
    float* __restrict__ att)
{
  __shared__ unsigned short Aa[128 * 32];
  __shared__ unsigned short Bt[128 * 32];

  const int tid  = threadIdx.x;
  const int lane = tid & 63, wv = tid >> 6;
  const int wr = wv >> 1, wc = wv & 1;
  const int quad = lane >> 4, lx = lane & 15;
  const int lr = lane >> 2, ls = lane & 3;
  const int lsw = ls ^ ((lr >> 1) & 3);

  // 768 blocks, 96/XCD = 2 batches/XCD; x fastest -> alpha-panel + x2T L2 reuse.
  const int lin = blockIdx.x;
  const int s   = (lin & 7) * 96 + (lin >> 3);
  const int d0  = (s % 6) * 128;
  const int i0  = ((s / 6) & 7) * 128;
  const int b   = s / 48;

  f32x4 acc[4][4] = {};

  for (int j0 = 0; j0 < L_; j0 += 32) {
    __syncthreads();
#pragma unroll
    for (int g = 0; g < 2; ++g) {
      const int rowl = wv * 32 + g * 16;
      const int row  = rowl + lr;
      const size_t ga = (size_t)(b * L_ + i0 + row) * L_ + j0 + lsw * 8;
      const size_t gb = ((size_t)(b * H_) + d0 + row) * L_ + j0 + lsw * 8;
      gld16(alphab + ga, &Aa[rowl * 32]);
      gld16(x2T + gb, &Bt[rowl * 32]);
    }
    __syncthreads();

    bf16x8 fa[4], fb[4];
#pragma unroll
    for (int t = 0; t < 4; ++t) {
      fa[t] = ld_frag_sw(Aa, wr * 64 + t * 16 + lx, quad);
      fb[t] = ld_frag_sw(Bt, wc * 64 + t * 16 + lx, quad);
    }
#pragma unroll
    for (int i = 0; i < 4; ++i)
#pragma unroll
      for (int j = 0; j < 4; ++j)
        acc[i][j] = MFMA(fa[i], fb[j], acc[i][j]);
  }

#pragma unroll
  for (int j = 0; j < 4; ++j) {
    const int dd = d0 + wc * 64 + j * 16 + lx;
#pragma unroll
    for (int i = 0; i < 4; ++i) {
      const int ib = i0 + wr * 64 + i * 16 + quad * 4;
#pragma unroll
      for (int r = 0; r < 4; ++r)
        att[((size_t)(b * L_) + ib + r) * H_ + dd] = acc[i][j][r];
    }
  }
}

// ---------------- K5: out = [x1, att, x1*att, x1-att] ---------------------------
__global__ __launch_bounds__(256) void k_concat(
    const float* __restrict__ x1, const float* __restrict__ att,
    float* __restrict__ out)
{
  const int gid = blockIdx.x * 256 + threadIdx.x;
  const int row = gid / 192;
  const int c   = (gid % 192) * 4;

  f32x4 xv = *(const f32x4*)(x1  + (size_t)row * H_ + c);
  f32x4 av = *(const f32x4*)(att + (size_t)row * H_ + c);
  f32x4 mv, sv;
#pragma unroll
  for (int q = 0; q < 4; ++q) { mv[q] = xv[q] * av[q]; sv[q] = xv[q] - av[q]; }

  float* ob = out + (size_t)row * (4 * H_) + c;
  *(f32x4*)(ob)          = xv;
  *(f32x4*)(ob + H_)     = av;
  *(f32x4*)(ob + 2 * H_) = mv;
  *(f32x4*)(ob + 3 * H_) = sv;
}

extern "C" void kernel_launch(void* const* d_in, const int* in_sizes, int n_in,
                              void* d_out, int out_size, void* d_ws, size_t ws_size,
                              hipStream_t stream) {
  const float* x1      = (const float*)d_in[0];
  const float* x2      = (const float*)d_in[1];
  // d_in[2] = x1_mask : unused
  const int*   x2_mask = (const int*)d_in[3];
  const float* W       = (const float*)d_in[4];
  const float* bias    = (const float*)d_in[5];
  float* out = (float*)d_out;

  char* o8 = (char*)d_out;
  unsigned short* Ph     = (unsigned short*)o8;                          // [0, 50331648)
  unsigned short* Pl     = (unsigned short*)(o8 + 50331648);             // [.., 100663296)
  float*          scores = (float*)(o8 + 100663296);                     // [.., 167772160)
  unsigned short* Xh     = (unsigned short*)(o8 + 100663296);            // alias (early)
  unsigned short* Wh     = (unsigned short*)(o8 + 167772160);            // 1.18 MB
  unsigned short* Wl     = (unsigned short*)(o8 + 168951808);            // 1.18 MB
  unsigned short* x2T    = (unsigned short*)(o8 + 170131456);            // 25.2 MB
  unsigned short* alphab = (unsigned short*)o8;                          // alias Ph (late)
  unsigned short* Xl     = (unsigned short*)d_ws;                        // [0, 50331648)
  float*          att    = (float*)d_ws;                                 // alias Xl (late)

  k_split  <<<dim3(XB_ + WB_ + TB_), 256, 0, stream>>>(x1, x2, W, Xh, Xl, Wh, Wl, x2T);
  k_proj   <<<dim3(384),   512, 0, stream>>>(Xh, Xl, Wh, Wl, bias, Ph, Pl);
  k_scores <<<dim3(256),   512, 0, stream>>>(Ph, Pl, x2_mask, scores);
  k_softmax<<<dim3(16384), 256, 0, stream>>>(scores, alphab);
  k_att    <<<dim3(768),   256, 0, stream>>>(alphab, x2T, att);
  k_concat <<<dim3(12288), 256, 0, stream>>>(x1, att, out);
}

// Round 2
// 588.484 us; speedup vs baseline: 1.0943x; 1.0943x over previous
//
#include <hip/hip_runtime.h>

// B=16, L1=L2=1024, H=768
// P = relu([x1;x2] @ W^T + b); S = P1·P2^T masked; softmax; att = alpha·x2;
// out = [x1, att, x1*att, x1-att]
//
// Numerics identical to the previous passing versions (hi/lo split-bf16 3-pass
// MFMA for proj+scores, order hh,hl,lh per 32-wide K-step; single-pass bf16 att).
//
// Round-2 changes (k_proj/k_scores only):
//  - fine per-phase interleave: each phase reads ONLY its pass's fragments,
//    issues 2-3 staged global_load_lds (queue order == read order), then
//    bar / MFMA / counted vmcnt / bar. Loads stay 2*CA+4 deep, never drained.
//  - k_proj re-tiled BM=128 x BN=256 -> grid 768 = exactly 3 blocks/CU
//    (was 384 = 1.5/CU imbalance). k_scores stays 256^2 -> 256 = 1/CU.
//
// d_out layout (lifetimes):
//   [0,50.3M)        Ph (proj->scores), then alpha_bf16 [0,33.5M) (softmax->att)
//   [50.3M,100.7M)   Pl
//   [100.7M,167.8M)  Xh (split->proj), then scores fp32 (scores->softmax)
//   [167.8M,169.0M)  Wh   [169.0M,170.1M) Wl   [170.1M,195.3M) x2T bf16
// d_ws: [0,50.3M) Xl (split->proj), then att fp32 (att->concat)

#define B_  16
#define L_  1024
#define H_  768
#define M1_ (B_ * L_)    // 16384
#define MT_ (2 * M1_)    // 32768

#define XB_  24576       // k_split blocks for X hi/lo
#define WB_  576         // k_split blocks for W hi/lo
#define TB_  3072        // k_split blocks for x2 transpose

using f32x4  = __attribute__((ext_vector_type(4))) float;
using bf16x8 = __attribute__((ext_vector_type(8))) __bf16;
using u16x8  = __attribute__((ext_vector_type(8))) unsigned short;
using u16x4  = __attribute__((ext_vector_type(4))) unsigned short;

__device__ inline unsigned short f2b(float f) {
  unsigned u = __builtin_bit_cast(unsigned, f);
  u += 0x7FFFu + ((u >> 16) & 1u);   // RNE; no NaN/inf in data
  return (unsigned short)(u >> 16);
}
__device__ inline float b2f(unsigned short u) {
  return __builtin_bit_cast(float, ((unsigned)u) << 16);
}

// async global->LDS, 16 B per lane; LDS dest = wave-uniform base + lane*16
__device__ inline void gld16(const void* g, void* l) {
  __builtin_amdgcn_global_load_lds(
      (__attribute__((address_space(1))) void*)g,
      (__attribute__((address_space(3))) void*)l, 16, 0, 0);
}

// Tile: [rows][32 u16] = 64 B/row, chunk (16B) swizzle: slot = chunk ^ ((row>>1)&3).
// ds_read_b128 fragment reads measured conflict-free (SQ_LDS_BANK_CONFLICT = 0).
__device__ inline bf16x8 ld_frag_sw(const unsigned short* lds, int row, int quad) {
  const int sl = quad ^ ((row >> 1) & 3);
  u16x8 v = *(const u16x8*)(lds + row * 32 + sl * 8);
  return __builtin_bit_cast(bf16x8, v);
}

#define MFMA(a, b, c) __builtin_amdgcn_mfma_f32_16x16x32_bf16((a), (b), (c), 0, 0, 0)

// Stage one (CH*16*8)x32-u16 matrix-half with 8 waves: CH gld16 per wave.
// Source chunk pre-swizzled (lsw) so linear LDS writes realize the read swizzle.
template<int CH>
__device__ __forceinline__ void stageH(const unsigned short* __restrict__ src,
                                       unsigned short* ldsbase,
                                       int wv, int lq, int lsw,
                                       size_t row0, int k0) {
#pragma unroll
  for (int g = 0; g < CH; ++g) {
    const int rowl = wv * (CH * 16) + g * 16;
    gld16(src + (row0 + rowl + lq) * (size_t)H_ + k0 + lsw * 8,
          ldsbase + rowl * 32);
  }
}

// BM = MI*32, BN = 256, BK = 32, hi/lo 3-pass K-loop. 8 waves (2M x 4N),
// per-wave output (MI*16) x 64. Double-buffered LDS, fine 3-phase schedule:
//   ph0: ds_read fah,fbh | issue Ah,Bh(t+1) | bar | 32..MFMA hh | vmcnt(2CA+2) | bar
//   ph1: ds_read fbl     | issue Bl(t+1)    | bar | MFMA hl     | vmcnt(CA+4)  | bar
//   ph2: ds_read fal     | issue Al(t+1)    | bar | MFMA lh     | vmcnt(CA+2)  | bar
// Per-wave load queue is always [Ah(CA),Bh(2),Bl(2),Al(CA)] in read order, so
// each counted wait retires exactly the half needed by the next phase's reads;
// the rest (2CA+4 deep) stays in flight across barriers. Last step drains
// CA -> 0 -> (none).
template<int MI>
__device__ __forceinline__ void gemm3_loop(
    const unsigned short* __restrict__ Agh, const unsigned short* __restrict__ Agl,
    const unsigned short* __restrict__ Bgh, const unsigned short* __restrict__ Bgl,
    size_t arow0, size_t brow0,
    unsigned short* SA, unsigned short* SB, f32x4 (&acc)[MI][4])
{
  constexpr int CA  = MI / 4;           // A-half gld16 per wave
  constexpr int HBA = (MI * 32) * 32;   // u16 per A half-buffer
  constexpr int HBB = 256 * 32;         // u16 per B half-buffer

  const int tid  = threadIdx.x;
  const int lane = tid & 63, wv = tid >> 6;
  const int wr = wv >> 2, wc = wv & 3;
  const int quad = lane >> 4, lx = lane & 15;
  const int lq  = lane >> 2;
  const int lsw = (lane & 3) ^ ((lane >> 3) & 3);

  // prologue: tile 0 -> buf 0; queue [Ah(CA), Bh(2), Bl(2), Al(CA)]
  stageH<CA>(Agh, SA,       wv, lq, lsw, arow0, 0);
  stageH<2 >(Bgh, SB,       wv, lq, lsw, brow0, 0);
  stageH<2 >(Bgl, SB + HBB, wv, lq, lsw, brow0, 0);
  stageH<CA>(Agl, SA + HBA, wv, lq, lsw, arow0, 0);
  asm volatile("s_waitcnt vmcnt(%0)" :: "i"(CA + 2) : "memory");  // Ah0,Bh0 landed
  __builtin_amdgcn_s_barrier();

  int c = 0;
  for (int t = 0; t < H_ / 32; ++t) {
    unsigned short* sAh = SA + c * (2 * HBA);
    unsigned short* sAl = sAh + HBA;
    unsigned short* sBh = SB + c * (2 * HBB);
    unsigned short* sBl = sBh + HBB;
    unsigned short* dA  = SA + (c ^ 1) * (2 * HBA);
    unsigned short* dB  = SB + (c ^ 1) * (2 * HBB);
    const int  k1   = t * 32 + 32;
    const bool more = (t < H_ / 32 - 1);

    // ---------------- phase 0 : hh ----------------
    bf16x8 fah[MI], fbh[4];
#pragma unroll
    for (int i = 0; i < MI; ++i)
      fah[i] = ld_frag_sw(sAh, wr * (MI * 16) + i * 16 + lx, quad);
#pragma unroll
    for (int j = 0; j < 4; ++j)
      fbh[j] = ld_frag_sw(sBh, wc * 64 + j * 16 + lx, quad);
    if (more) {
      stageH<CA>(Agh, dA, wv, lq, lsw, arow0, k1);
      stageH<2 >(Bgh, dB, wv, lq, lsw, brow0, k1);
    }
    __builtin_amdgcn_s_barrier();
    __builtin_amdgcn_s_setprio(1);
#pragma unroll
    for (int i = 0; i < MI; ++i)
#pragma unroll
      for (int j = 0; j < 4; ++j) acc[i][j] = MFMA(fah[i], fbh[j], acc[i][j]);
    __builtin_amdgcn_s_setprio(0);
    if (more) asm volatile("s_waitcnt vmcnt(%0)" :: "i"(2 * CA + 2) : "memory");
    else      asm volatile("s_waitcnt vmcnt(%0)" :: "i"(CA)         : "memory");
    __builtin_amdgcn_s_barrier();

    // ---------------- phase 1 : hl ----------------
    bf16x8 fbl[4];
#pragma unroll
    for (int j = 0; j < 4; ++j)
      fbl[j] = ld_frag_sw(sBl, wc * 64 + j * 16 + lx, quad);
    if (more) stageH<2>(Bgl, dB + HBB, wv, lq, lsw, brow0, k1);
    __builtin_amdgcn_s_barrier();
    __builtin_amdgcn_s_setprio(1);
#pragma unroll
    for (int i = 0; i < MI; ++i)
#pragma unroll
      for (int j = 0; j < 4; ++j) acc[i][j] = MFMA(fah[i], fbl[j], acc[i][j]);
    __builtin_amdgcn_s_setprio(0);
    if (more) asm volatile("s_waitcnt vmcnt(%0)" :: "i"(CA + 4) : "memory");
    else      asm volatile("s_waitcnt vmcnt(0)" ::: "memory");
    __builtin_amdgcn_s_barrier();

    // ---------------- phase 2 : lh ----------------
    bf16x8 fal[MI];
#pragma unroll
    for (int i = 0; i < MI; ++i)
      fal[i] = ld_frag_sw(sAl, wr * (MI * 16) + i * 16 + lx, quad);
    if (more) stageH<CA>(Agl, dA + HBA, wv, lq, lsw, arow0, k1);
    __builtin_amdgcn_s_barrier();
    __builtin_amdgcn_s_setprio(1);
#pragma unroll
    for (int i = 0; i < MI; ++i)
#pragma unroll
      for (int j = 0; j < 4; ++j) acc[i][j] = MFMA(fal[i], fbh[j], acc[i][j]);
    __builtin_amdgcn_s_setprio(0);
    if (more) asm volatile("s_waitcnt vmcnt(%0)" :: "i"(CA + 2) : "memory");
    __builtin_amdgcn_s_barrier();

    c ^= 1;
  }
}

// ---------------- K0: split X,W into hi/lo bf16; build x2T bf16 -----------------
__global__ __launch_bounds__(256) void k_split(
    const float* __restrict__ x1, const float* __restrict__ x2,
    const float* __restrict__ W,
    unsigned short* __restrict__ Xh, unsigned short* __restrict__ Xl,
    unsigned short* __restrict__ Wh, unsigned short* __restrict__ Wl,
    unsigned short* __restrict__ x2T)
{
  __shared__ unsigned short tile[64][72];
  const int tid = threadIdx.x;
  const int bx  = blockIdx.x;

  if (bx < XB_) {
    const size_t idx = (size_t)bx * 256 + tid;          // f32x4 index over [32768][768]
    const int row = (int)(idx / 192);
    const int col = ((int)(idx % 192)) * 4;
    const float* src = (row < M1_) ? (x1 + (size_t)row * H_ + col)
                                   : (x2 + (size_t)(row - M1_) * H_ + col);
    f32x4 v = *(const f32x4*)src;
    u16x4 h, l;
#pragma unroll
    for (int q = 0; q < 4; ++q) { h[q] = f2b(v[q]); l[q] = f2b(v[q] - b2f(h[q])); }
    *(u16x4*)(Xh + idx * 4) = h;
    *(u16x4*)(Xl + idx * 4) = l;
  } else if (bx < XB_ + WB_) {
    const int idx = (bx - XB_) * 256 + tid;
    f32x4 v = *(const f32x4*)(W + (size_t)idx * 4);
    u16x4 h, l;
#pragma unroll
    for (int q = 0; q < 4; ++q) { h[q] = f2b(v[q]); l[q] = f2b(v[q] - b2f(h[q])); }
    *(u16x4*)(Wh + (size_t)idx * 4) = h;
    *(u16x4*)(Wl + (size_t)idx * 4) = l;
  } else {
    const int t  = bx - (XB_ + WB_);
    const int b  = t / 192;
    const int r  = t % 192;
    const int j0 = (r / 12) * 64;
    const int d0 = (r % 12) * 64;
#pragma unroll
    for (int p = 0; p < 4; ++p) {
      const int idx = tid + p * 256;
      const int jr  = idx >> 4;
      const int dc  = (idx & 15) * 4;
      f32x4 v = *(const f32x4*)(x2 + ((size_t)(b * L_ + j0 + jr)) * H_ + d0 + dc);
#pragma unroll
      for (int q = 0; q < 4; ++q) tile[jr][dc + q] = f2b(v[q]);
    }
    __syncthreads();
#pragma unroll
    for (int p = 0; p < 2; ++p) {
      const int idx = tid + p * 256;
      const int dr  = idx >> 3;
      const int jc  = (idx & 7) * 8;
      u16x8 o;
#pragma unroll
      for (int q = 0; q < 8; ++q) o[q] = tile[jc + q][dr];
      *(u16x8*)(x2T + ((size_t)(b * H_) + d0 + dr) * L_ + j0 + jc) = o;
    }
  }
}

// ---------------- K1: P = relu(X @ W^T + b), 3-pass hi/lo, store Ph/Pl ----------
// BM=128 x BN=256 -> 256x3 = 768 blocks = exactly 3 blocks/CU.
__global__ __launch_bounds__(512, 2) void k_proj(
    const unsigned short* __restrict__ Xh, const unsigned short* __restrict__ Xl,
    const unsigned short* __restrict__ Wh, const unsigned short* __restrict__ Wl,
    const float* __restrict__ bias,
    unsigned short* __restrict__ Ph, unsigned short* __restrict__ Pl)
{
  __shared__ unsigned short SA[2 * 2 * 128 * 32];   // 32 KB
  __shared__ unsigned short SB[2 * 2 * 256 * 32];   // 64 KB

  const int tid  = threadIdx.x;
  const int lane = tid & 63, wv = tid >> 6;
  const int wr = wv >> 2, wc = wv & 3;
  const int quad = lane >> 4, lx = lane & 15;

  // XCD-chunked bijective swizzle: 768 blocks, 96/XCD; n fastest within an
  // m-panel -> the X 128-row panel is read 3x from the same XCD's L2.
  const int lin = blockIdx.x;
  const int s   = (lin & 7) * 96 + (lin >> 3);
  const int n0  = (s % 3) * 256;
  const int m0  = (s / 3) * 128;

  f32x4 acc[4][4] = {};
  gemm3_loop<4>(Xh, Xl, Wh, Wl, (size_t)m0, (size_t)n0, SA, SB, acc);

#pragma unroll
  for (int j = 0; j < 4; ++j) {
    const int h = n0 + wc * 64 + j * 16 + lx;
    const float bv = bias[h];
#pragma unroll
    for (int i = 0; i < 4; ++i) {
      const int mrow = m0 + wr * 64 + i * 16 + quad * 4;
#pragma unroll
      for (int r = 0; r < 4; ++r) {
        float v = acc[i][j][r] + bv;
        v = v > 0.f ? v : 0.f;
        const unsigned short hh = f2b(v);
        const unsigned short ll = f2b(v - b2f(hh));
        const size_t off = (size_t)(mrow + r) * H_ + h;
        Ph[off] = hh;
        Pl[off] = ll;
      }
    }
  }
}

// ---------------- K2: scores = P1·P2^T (3-pass), masked -------------------------
// 256^2 tile -> 256 blocks = exactly 1 block/CU.
__global__ __launch_bounds__(512, 2) void k_scores(
    const unsigned short* __restrict__ Ph, const unsigned short* __restrict__ Pl,
    const int* __restrict__ x2_mask, float* __restrict__ scores)
{
  __shared__ unsigned short SA[2 * 2 * 256 * 32];   // 64 KB
  __shared__ unsigned short SB[2 * 2 * 256 * 32];   // 64 KB

  const int tid  = threadIdx.x;
  const int lane = tid & 63, wv = tid >> 6;
  const int wr = wv >> 2, wc = wv & 3;
  const int quad = lane >> 4, lx = lane & 15;

  // 256 blocks, 32/XCD = 2 full batches per XCD; j fastest -> i-panel L2 reuse.
  const int lin = blockIdx.x;
  const int s   = (lin & 7) * 32 + (lin >> 3);
  const int j0  = (s & 3) * 256;
  const int i0  = ((s >> 2) & 3) * 256;
  const int b   = s >> 4;

  f32x4 acc[8][4] = {};
  gemm3_loop<8>(Ph, Pl, Ph, Pl,
                (size_t)(b * L_ + i0), (size_t)(M1_ + b * L_ + j0), SA, SB, acc);

#pragma unroll
  for (int j = 0; j < 4; ++j) {
    const int jj = j0 + wc * 64 + j * 16 + lx;
    const int mv = x2_mask[b * L_ + jj];
#pragma unroll
    for (int i = 0; i < 8; ++i) {
      const int ib = i0 + wr * 128 + i * 16 + quad * 4;
#pragma unroll
      for (int r = 0; r < 4; ++r) {
        const float v = mv ? -1e30f : acc[i][j][r];
        scores[((size_t)(b * L_) + ib + r) * L_ + jj] = v;
      }
    }
  }
}

// ---------------- K3: row softmax, fp32 in -> bf16 alpha out --------------------
__global__ __launch_bounds__(256) void k_softmax(
    const float* __restrict__ scores, unsigned short* __restrict__ alphab)
{
  const size_t row = blockIdx.x;
  const float* p = scores + row * L_;
  const int tid = threadIdx.x;

  f32x4 v = *(const f32x4*)(p + tid * 4);
  float m = fmaxf(fmaxf(v[0], v[1]), fmaxf(v[2], v[3]));
#pragma unroll
  for (int off = 32; off > 0; off >>= 1) m = fmaxf(m, __shfl_down(m, off));

  __shared__ float rmax[4];
  __shared__ float rsum[4];
  const int wid = tid >> 6, lane = tid & 63;
  if (lane == 0) rmax[wid] = m;
  __syncthreads();
  m = fmaxf(fmaxf(rmax[0], rmax[1]), fmaxf(rmax[2], rmax[3]));

  f32x4 e;
#pragma unroll
  for (int q = 0; q < 4; ++q) e[q] = __expf(v[q] - m);
  float s = e[0] + e[1] + e[2] + e[3];
#pragma unroll
  for (int off = 32; off > 0; off >>= 1) s += __shfl_down(s, off);
  if (lane == 0) rsum[wid] = s;
  __syncthreads();
  s = rsum[0] + rsum[1] + rsum[2] + rsum[3];

  const float inv = 1.0f / s;
  u16x4 o;
#pragma unroll
  for (int q = 0; q < 4; ++q) o[q] = f2b(e[q] * inv);
  *(u16x4*)(alphab + row * L_ + tid * 4) = o;
}

// ---------------- K4: att = alpha @ x2 (bf16 single-pass) -----------------------
__global__ __launch_bounds__(256) void k_att(
    const unsigned short* __restrict__ alphab, const unsigned short* __restrict__ x2T,
    float* __restrict__ att)
{
  __shared__ unsigned short Aa[128 * 32];
  __shared__ unsigned short Bt[128 * 32];

  const int tid  = threadIdx.x;
  const int lane = tid & 63, wv = tid >> 6;
  const int wr = wv >> 1, wc = wv & 1;
  const int quad = lane >> 4, lx = lane & 15;
  const int lr = lane >> 2, ls = lane & 3;
  const int lsw = ls ^ ((lr >> 1) & 3);

  // 768 blocks, 96/XCD = 2 batches/XCD; d fastest -> alpha-panel + x2T L2 reuse.
  const int lin = blockIdx.x;
  const int s   = (lin & 7) * 96 + (lin >> 3);
  const int d0  = (s % 6) * 128;
  const int i0  = ((s / 6) & 7) * 128;
  const int b   = s / 48;

  f32x4 acc[4][4] = {};

  for (int j0 = 0; j0 < L_; j0 += 32) {
    __syncthreads();
#pragma unroll
    for (int g = 0; g < 2; ++g) {
      const int rowl = wv * 32 + g * 16;
      const int row  = rowl + lr;
      const size_t ga = (size_t)(b * L_ + i0 + row) * L_ + j0 + lsw * 8;
      const size_t gb = ((size_t)(b * H_) + d0 + row) * L_ + j0 + lsw * 8;
      gld16(alphab + ga, &Aa[rowl * 32]);
      gld16(x2T + gb, &Bt[rowl * 32]);
    }
    __syncthreads();

    bf16x8 fa[4], fb[4];
#pragma unroll
    for (int t = 0; t < 4; ++t) {
      fa[t] = ld_frag_sw(Aa, wr * 64 + t * 16 + lx, quad);
      fb[t] = ld_frag_sw(Bt, wc * 64 + t * 16 + lx, quad);
    }
#pragma unroll
    for (int i = 0; i < 4; ++i)
#pragma unroll
      for (int j = 0; j < 4; ++j)
        acc[i][j] = MFMA(fa[i], fb[j], acc[i][j]);
  }

#pragma unroll
  for (int j = 0; j < 4; ++j) {
    const int dd = d0 + wc * 64 + j * 16 + lx;
#pragma unroll
    for (int i = 0; i < 4; ++i) {
      const int ib = i0 + wr * 64 + i * 16 + quad * 4;
#pragma unroll
      for (int r = 0; r < 4; ++r)
        att[((size_t)(b * L_) + ib + r) * H_ + dd] = acc[i][j][r];
    }
  }
}

// ---------------- K5: out = [x1, att, x1*att, x1-att] ---------------------------
__global__ __launch_bounds__(256) void k_concat(
    const float* __restrict__ x1, const float* __restrict__ att,
    float* __restrict__ out)
{
  const int gid = blockIdx.x * 256 + threadIdx.x;
  const int row = gid / 192;
  const int c   = (gid % 192) * 4;

  f32x4 xv = *(const f32x4*)(x1  + (size_t)row * H_ + c);
  f32x4 av = *(const f32x4*)(att + (size_t)row * H_ + c);
  f32x4 mv, sv;
#pragma unroll
  for (int q = 0; q < 4; ++q) { mv[q] = xv[q] * av[q]; sv[q] = xv[q] - av[q]; }

  float* ob = out + (size_t)row * (4 * H_) + c;
  *(f32x4*)(ob)          = xv;
  *(f32x4*)(ob + H_)     = av;
  *(f32x4*)(ob + 2 * H_) = mv;
  *(f32x4*)(ob + 3 * H_) = sv;
}

extern "C" void kernel_launch(void* const* d_in, const int* in_sizes, int n_in,
                              void* d_out, int out_size, void* d_ws, size_t ws_size,
                              hipStream_t stream) {
  const float* x1      = (const float*)d_in[0];
  const float* x2      = (const float*)d_in[1];
  // d_in[2] = x1_mask : unused
  const int*   x2_mask = (const int*)d_in[3];
  const float* W       = (const float*)d_in[4];
  const float* bias    = (const float*)d_in[5];
  float* out = (float*)d_out;

  char* o8 = (char*)d_out;
  unsigned short* Ph     = (unsigned short*)o8;                          // [0, 50331648)
  unsigned short* Pl     = (unsigned short*)(o8 + 50331648);             // [.., 100663296)
  float*          scores = (float*)(o8 + 100663296);                     // [.., 167772160)
  unsigned short* Xh     = (unsigned short*)(o8 + 100663296);            // alias (early)
  unsigned short* Wh     = (unsigned short*)(o8 + 167772160);            // 1.18 MB
  unsigned short* Wl     = (unsigned short*)(o8 + 168951808);            // 1.18 MB
  unsigned short* x2T    = (unsigned short*)(o8 + 170131456);            // 25.2 MB
  unsigned short* alphab = (unsigned short*)o8;                          // alias Ph (late)
  unsigned short* Xl     = (unsigned short*)d_ws;                        // [0, 50331648)
  float*          att    = (float*)d_ws;                                 // alias Xl (late)

  k_split  <<<dim3(XB_ + WB_ + TB_), 256, 0, stream>>>(x1, x2, W, Xh, Xl, Wh, Wl, x2T);
  k_proj   <<<dim3(768),   512, 0, stream>>>(Xh, Xl, Wh, Wl, bias, Ph, Pl);
  k_scores <<<dim3(256),   512, 0, stream>>>(Ph, Pl, x2_mask, scores);
  k_softmax<<<dim3(16384), 256, 0, stream>>>(scores, alphab);
  k_att    <<<dim3(768),   256, 0, stream>>>(alphab, x2T, att);
  k_concat <<<dim3(12288), 256, 0, stream>>>(x1, att, out);
}

// Round 3
// 586.853 us; speedup vs baseline: 1.0973x; 1.0028x over previous
//
#include <hip/hip_runtime.h>

// B=16, L1=L2=1024, H=768
// P = relu([x1;x2] @ W^T + b); S = P1·P2^T masked; softmax; att = alpha·x2;
// out = [x1, att, x1*att, x1-att]
//
// Numerics identical to the previous passing versions (hi/lo split-bf16 3-pass
// MFMA for proj+scores, order hh,hl,lh per 32-wide K-step; single-pass bf16 att).
//
// Round-3 changes:
//  - gemm3_loop: phases merged 3->2 (hh | hl+lh), barriers 6->2 per K-step.
//    Both counted waits become vmcnt(CA+2); queue [Ah,Bh|Bl,Al] == read order.
//    The dropped pre-MFMA barriers were redundant: the only cross-wave hazard
//    is "other waves' gld16 landed before my next-phase ds_read", which the
//    [own vmcnt -> barrier] pair already guarantees.
//  - k_att: triple-buffered counted-vmcnt loop (1 barrier/step, never drains
//    until the tail) instead of 2x __syncthreads + implicit drain per step.
//  - optional fused k_attcat (att GEMM + concat epilogue) eliminating the
//    100 MB att round-trip and the k_concat kernel. Requires alpha+x2T to
//    live in d_ws (out overwrites ALL of d_out): host branches on
//    ws_size >= 75.5 MB; otherwise the round-2 path runs unchanged.
//
// d_out layout (lifetimes), non-fused path:
//   [0,50.3M)        Ph (proj->scores), then alpha_bf16 [0,33.5M) (softmax->att)
//   [50.3M,100.7M)   Pl
//   [100.7M,167.8M)  Xh (split->proj), then scores fp32 (scores->softmax)
//   [167.8M,169.0M)  Wh   [169.0M,170.1M) Wl   [170.1M,195.3M) x2T bf16
// d_ws: [0,50.3M) Xl (split->proj), then att fp32 (att->concat)
//
// fused path: alpha -> d_ws[0,33.5M) (after Xl dies), x2T -> d_ws[50.3M,75.5M),
// out written over all of d_out by k_attcat.

#define B_  16
#define L_  1024
#define H_  768
#define M1_ (B_ * L_)    // 16384
#define MT_ (2 * M1_)    // 32768

#define XB_  24576       // k_split blocks for X hi/lo
#define WB_  576         // k_split blocks for W hi/lo
#define TB_  3072        // k_split blocks for x2 transpose

using f32x4  = __attribute__((ext_vector_type(4))) float;
using bf16x8 = __attribute__((ext_vector_type(8))) __bf16;
using u16x8  = __attribute__((ext_vector_type(8))) unsigned short;
using u16x4  = __attribute__((ext_vector_type(4))) unsigned short;

__device__ inline unsigned short f2b(float f) {
  unsigned u = __builtin_bit_cast(unsigned, f);
  u += 0x7FFFu + ((u >> 16) & 1u);   // RNE; no NaN/inf in data
  return (unsigned short)(u >> 16);
}
__device__ inline float b2f(unsigned short u) {
  return __builtin_bit_cast(float, ((unsigned)u) << 16);
}

// async global->LDS, 16 B per lane; LDS dest = wave-uniform base + lane*16
__device__ inline void gld16(const void* g, void* l) {
  __builtin_amdgcn_global_load_lds(
      (__attribute__((address_space(1))) void*)g,
      (__attribute__((address_space(3))) void*)l, 16, 0, 0);
}

// Tile: [rows][32 u16] = 64 B/row, chunk (16B) swizzle: slot = chunk ^ ((row>>1)&3).
// ds_read_b128 fragment reads measured conflict-free (SQ_LDS_BANK_CONFLICT = 0).
__device__ inline bf16x8 ld_frag_sw(const unsigned short* lds, int row, int quad) {
  const int sl = quad ^ ((row >> 1) & 3);
  u16x8 v = *(const u16x8*)(lds + row * 32 + sl * 8);
  return __builtin_bit_cast(bf16x8, v);
}

#define MFMA(a, b, c) __builtin_amdgcn_mfma_f32_16x16x32_bf16((a), (b), (c), 0, 0, 0)

// Stage one (CH*16*8)x32-u16 matrix-half with 8 waves: CH gld16 per wave.
// Source chunk pre-swizzled (lsw) so linear LDS writes realize the read swizzle.
template<int CH>
__device__ __forceinline__ void stageH(const unsigned short* __restrict__ src,
                                       unsigned short* ldsbase,
                                       int wv, int lq, int lsw,
                                       size_t row0, int k0) {
#pragma unroll
  for (int g = 0; g < CH; ++g) {
    const int rowl = wv * (CH * 16) + g * 16;
    gld16(src + (row0 + rowl + lq) * (size_t)H_ + k0 + lsw * 8,
          ldsbase + rowl * 32);
  }
}

// BM = MI*32, BN = 256, BK = 32, hi/lo 3-pass K-loop. 8 waves (2M x 4N),
// per-wave output (MI*16) x 64. Double-buffered LDS, 2-phase schedule:
//   ph0: ds_read fah,fbh | issue Ah,Bh(t+1) | MFMA hh        | vmcnt(CA+2) | bar
//   ph1: ds_read fbl | issue Bl(t+1) | MFMA hl |
//        ds_read fal | issue Al(t+1) | MFMA lh | vmcnt(CA+2) | bar
// Per-wave load queue is always [Ah(CA),Bh(2),Bl(2),Al(CA)] in read order;
// each wait retires exactly the group the next phase reads; 2CA+4 deep max,
// >= CA+2 always in flight. Last step: ph0 waits vmcnt(0), ph1 waits nothing.
template<int MI>
__device__ __forceinline__ void gemm3_loop(
    const unsigned short* __restrict__ Agh, const unsigned short* __restrict__ Agl,
    const unsigned short* __restrict__ Bgh, const unsigned short* __restrict__ Bgl,
    size_t arow0, size_t brow0,
    unsigned short* SA, unsigned short* SB, f32x4 (&acc)[MI][4])
{
  constexpr int CA  = MI / 4;           // A-half gld16 per wave
  constexpr int HBA = (MI * 32) * 32;   // u16 per A half-buffer
  constexpr int HBB = 256 * 32;         // u16 per B half-buffer

  const int tid  = threadIdx.x;
  const int lane = tid & 63, wv = tid >> 6;
  const int wr = wv >> 2, wc = wv & 3;
  const int quad = lane >> 4, lx = lane & 15;
  const int lq  = lane >> 2;
  const int lsw = (lane & 3) ^ ((lane >> 3) & 3);

  // prologue: tile 0 -> buf 0; queue [Ah(CA), Bh(2), Bl(2), Al(CA)]
  stageH<CA>(Agh, SA,       wv, lq, lsw, arow0, 0);
  stageH<2 >(Bgh, SB,       wv, lq, lsw, brow0, 0);
  stageH<2 >(Bgl, SB + HBB, wv, lq, lsw, brow0, 0);
  stageH<CA>(Agl, SA + HBA, wv, lq, lsw, arow0, 0);
  asm volatile("s_waitcnt vmcnt(%0)" :: "i"(CA + 2) : "memory");  // Ah0,Bh0 landed
  __builtin_amdgcn_s_barrier();

  int c = 0;
  for (int t = 0; t < H_ / 32; ++t) {
    unsigned short* sAh = SA + c * (2 * HBA);
    unsigned short* sAl = sAh + HBA;
    unsigned short* sBh = SB + c * (2 * HBB);
    unsigned short* sBl = sBh + HBB;
    unsigned short* dA  = SA + (c ^ 1) * (2 * HBA);
    unsigned short* dB  = SB + (c ^ 1) * (2 * HBB);
    const int  k1   = t * 32 + 32;
    const bool more = (t < H_ / 32 - 1);

    // ---------------- phase 0 : hh ----------------
    bf16x8 fah[MI], fbh[4];
#pragma unroll
    for (int i = 0; i < MI; ++i)
      fah[i] = ld_frag_sw(sAh, wr * (MI * 16) + i * 16 + lx, quad);
#pragma unroll
    for (int j = 0; j < 4; ++j)
      fbh[j] = ld_frag_sw(sBh, wc * 64 + j * 16 + lx, quad);
    if (more) {
      stageH<CA>(Agh, dA, wv, lq, lsw, arow0, k1);
      stageH<2 >(Bgh, dB, wv, lq, lsw, brow0, k1);
    }
    __builtin_amdgcn_s_setprio(1);
#pragma unroll
    for (int i = 0; i < MI; ++i)
#pragma unroll
      for (int j = 0; j < 4; ++j) acc[i][j] = MFMA(fah[i], fbh[j], acc[i][j]);
    __builtin_amdgcn_s_setprio(0);
    if (more) asm volatile("s_waitcnt vmcnt(%0)" :: "i"(CA + 2) : "memory");
    else      asm volatile("s_waitcnt vmcnt(0)" ::: "memory");
    __builtin_amdgcn_s_barrier();

    // ---------------- phase 1 : hl + lh ----------------
    bf16x8 fbl[4];
#pragma unroll
    for (int j = 0; j < 4; ++j)
      fbl[j] = ld_frag_sw(sBl, wc * 64 + j * 16 + lx, quad);
    if (more) stageH<2>(Bgl, dB + HBB, wv, lq, lsw, brow0, k1);
    __builtin_amdgcn_s_setprio(1);
#pragma unroll
    for (int i = 0; i < MI; ++i)
#pragma unroll
      for (int j = 0; j < 4; ++j) acc[i][j] = MFMA(fah[i], fbl[j], acc[i][j]);
    __builtin_amdgcn_s_setprio(0);

    bf16x8 fal[MI];
#pragma unroll
    for (int i = 0; i < MI; ++i)
      fal[i] = ld_frag_sw(sAl, wr * (MI * 16) + i * 16 + lx, quad);
    if (more) stageH<CA>(Agl, dA + HBA, wv, lq, lsw, arow0, k1);
    __builtin_amdgcn_s_setprio(1);
#pragma unroll
    for (int i = 0; i < MI; ++i)
#pragma unroll
      for (int j = 0; j < 4; ++j) acc[i][j] = MFMA(fal[i], fbh[j], acc[i][j]);
    __builtin_amdgcn_s_setprio(0);
    if (more) {
      asm volatile("s_waitcnt vmcnt(%0)" :: "i"(CA + 2) : "memory");
      __builtin_amdgcn_s_barrier();
    }
    c ^= 1;
  }
}

// ---------------- K0: split X,W into hi/lo bf16; build x2T bf16 -----------------
__global__ __launch_bounds__(256) void k_split(
    const float* __restrict__ x1, const float* __restrict__ x2,
    const float* __restrict__ W,
    unsigned short* __restrict__ Xh, unsigned short* __restrict__ Xl,
    unsigned short* __restrict__ Wh, unsigned short* __restrict__ Wl,
    unsigned short* __restrict__ x2T)
{
  __shared__ unsigned short tile[64][72];
  const int tid = threadIdx.x;
  const int bx  = blockIdx.x;

  if (bx < XB_) {
    const size_t idx = (size_t)bx * 256 + tid;          // f32x4 index over [32768][768]
    const int row = (int)(idx / 192);
    const int col = ((int)(idx % 192)) * 4;
    const float* src = (row < M1_) ? (x1 + (size_t)row * H_ + col)
                                   : (x2 + (size_t)(row - M1_) * H_ + col);
    f32x4 v = *(const f32x4*)src;
    u16x4 h, l;
#pragma unroll
    for (int q = 0; q < 4; ++q) { h[q] = f2b(v[q]); l[q] = f2b(v[q] - b2f(h[q])); }
    *(u16x4*)(Xh + idx * 4) = h;
    *(u16x4*)(Xl + idx * 4) = l;
  } else if (bx < XB_ + WB_) {
    const int idx = (bx - XB_) * 256 + tid;
    f32x4 v = *(const f32x4*)(W + (size_t)idx * 4);
    u16x4 h, l;
#pragma unroll
    for (int q = 0; q < 4; ++q) { h[q] = f2b(v[q]); l[q] = f2b(v[q] - b2f(h[q])); }
    *(u16x4*)(Wh + (size_t)idx * 4) = h;
    *(u16x4*)(Wl + (size_t)idx * 4) = l;
  } else {
    const int t  = bx - (XB_ + WB_);
    const int b  = t / 192;
    const int r  = t % 192;
    const int j0 = (r / 12) * 64;
    const int d0 = (r % 12) * 64;
#pragma unroll
    for (int p = 0; p < 4; ++p) {
      const int idx = tid + p * 256;
      const int jr  = idx >> 4;
      const int dc  = (idx & 15) * 4;
      f32x4 v = *(const f32x4*)(x2 + ((size_t)(b * L_ + j0 + jr)) * H_ + d0 + dc);
#pragma unroll
      for (int q = 0; q < 4; ++q) tile[jr][dc + q] = f2b(v[q]);
    }
    __syncthreads();
#pragma unroll
    for (int p = 0; p < 2; ++p) {
      const int idx = tid + p * 256;
      const int dr  = idx >> 3;
      const int jc  = (idx & 7) * 8;
      u16x8 o;
#pragma unroll
      for (int q = 0; q < 8; ++q) o[q] = tile[jc + q][dr];
      *(u16x8*)(x2T + ((size_t)(b * H_) + d0 + dr) * L_ + j0 + jc) = o;
    }
  }
}

// ---------------- K1: P = relu(X @ W^T + b), 3-pass hi/lo, store Ph/Pl ----------
// BM=128 x BN=256 -> 256x3 = 768 blocks = exactly 3 blocks/CU.
__global__ __launch_bounds__(512, 2) void k_proj(
    const unsigned short* __restrict__ Xh, const unsigned short* __restrict__ Xl,
    const unsigned short* __restrict__ Wh, const unsigned short* __restrict__ Wl,
    const float* __restrict__ bias,
    unsigned short* __restrict__ Ph, unsigned short* __restrict__ Pl)
{
  __shared__ unsigned short SA[2 * 2 * 128 * 32];   // 32 KB
  __shared__ unsigned short SB[2 * 2 * 256 * 32];   // 64 KB

  const int tid  = threadIdx.x;
  const int lane = tid & 63, wv = tid >> 6;
  const int wr = wv >> 2, wc = wv & 3;
  const int quad = lane >> 4, lx = lane & 15;

  // XCD-chunked bijective swizzle: 768 blocks, 96/XCD; n fastest within an
  // m-panel -> the X 128-row panel is read 3x from the same XCD's L2.
  const int lin = blockIdx.x;
  const int s   = (lin & 7) * 96 + (lin >> 3);
  const int n0  = (s % 3) * 256;
  const int m0  = (s / 3) * 128;

  f32x4 acc[4][4] = {};
  gemm3_loop<4>(Xh, Xl, Wh, Wl, (size_t)m0, (size_t)n0, SA, SB, acc);

#pragma unroll
  for (int j = 0; j < 4; ++j) {
    const int h = n0 + wc * 64 + j * 16 + lx;
    const float bv = bias[h];
#pragma unroll
    for (int i = 0; i < 4; ++i) {
      const int mrow = m0 + wr * 64 + i * 16 + quad * 4;
#pragma unroll
      for (int r = 0; r < 4; ++r) {
        float v = acc[i][j][r] + bv;
        v = v > 0.f ? v : 0.f;
        const unsigned short hh = f2b(v);
        const unsigned short ll = f2b(v - b2f(hh));
        const size_t off = (size_t)(mrow + r) * H_ + h;
        Ph[off] = hh;
        Pl[off] = ll;
      }
    }
  }
}

// ---------------- K2: scores = P1·P2^T (3-pass), masked -------------------------
// 256^2 tile -> 256 blocks = exactly 1 block/CU.
__global__ __launch_bounds__(512, 2) void k_scores(
    const unsigned short* __restrict__ Ph, const unsigned short* __restrict__ Pl,
    const int* __restrict__ x2_mask, float* __restrict__ scores)
{
  __shared__ unsigned short SA[2 * 2 * 256 * 32];   // 64 KB
  __shared__ unsigned short SB[2 * 2 * 256 * 32];   // 64 KB

  const int tid  = threadIdx.x;
  const int lane = tid & 63, wv = tid >> 6;
  const int wr = wv >> 2, wc = wv & 3;
  const int quad = lane >> 4, lx = lane & 15;

  // 256 blocks, 32/XCD = 2 full batches per XCD; j fastest -> i-panel L2 reuse.
  const int lin = blockIdx.x;
  const int s   = (lin & 7) * 32 + (lin >> 3);
  const int j0  = (s & 3) * 256;
  const int i0  = ((s >> 2) & 3) * 256;
  const int b   = s >> 4;

  f32x4 acc[8][4] = {};
  gemm3_loop<8>(Ph, Pl, Ph, Pl,
                (size_t)(b * L_ + i0), (size_t)(M1_ + b * L_ + j0), SA, SB, acc);

#pragma unroll
  for (int j = 0; j < 4; ++j) {
    const int jj = j0 + wc * 64 + j * 16 + lx;
    const int mv = x2_mask[b * L_ + jj];
#pragma unroll
    for (int i = 0; i < 8; ++i) {
      const int ib = i0 + wr * 128 + i * 16 + quad * 4;
#pragma unroll
      for (int r = 0; r < 4; ++r) {
        const float v = mv ? -1e30f : acc[i][j][r];
        scores[((size_t)(b * L_) + ib + r) * L_ + jj] = v;
      }
    }
  }
}

// ---------------- K3: row softmax, fp32 in -> bf16 alpha out --------------------
__global__ __launch_bounds__(256) void k_softmax(
    const float* __restrict__ scores, unsigned short* __restrict__ alphab)
{
  const size_t row = blockIdx.x;
  const float* p = scores + row * L_;
  const int tid = threadIdx.x;

  f32x4 v = *(const f32x4*)(p + tid * 4);
  float m = fmaxf(fmaxf(v[0], v[1]), fmaxf(v[2], v[3]));
#pragma unroll
  for (int off = 32; off > 0; off >>= 1) m = fmaxf(m, __shfl_down(m, off));

  __shared__ float rmax[4];
  __shared__ float rsum[4];
  const int wid = tid >> 6, lane = tid & 63;
  if (lane == 0) rmax[wid] = m;
  __syncthreads();
  m = fmaxf(fmaxf(rmax[0], rmax[1]), fmaxf(rmax[2], rmax[3]));

  f32x4 e;
#pragma unroll
  for (int q = 0; q < 4; ++q) e[q] = __expf(v[q] - m);
  float s = e[0] + e[1] + e[2] + e[3];
#pragma unroll
  for (int off = 32; off > 0; off >>= 1) s += __shfl_down(s, off);
  if (lane == 0) rsum[wid] = s;
  __syncthreads();
  s = rsum[0] + rsum[1] + rsum[2] + rsum[3];

  const float inv = 1.0f / s;
  u16x4 o;
#pragma unroll
  for (int q = 0; q < 4; ++q) o[q] = f2b(e[q] * inv);
  *(u16x4*)(alphab + row * L_ + tid * 4) = o;
}

// ------- att GEMM inner loop: triple-buffered, counted vmcnt, 1 barrier/step ----
// 4 waves (2x2), per-wave 64x64 out; LDS 3 x (Aa 8KB + Bt 8KB) = 48 KB.
// Per step: read fa,fb from buf t%3 | stage j0=(t+2)*32 into buf (t+2)%3 |
// 16 MFMA | vmcnt(4) [retires step t+1's 4 loads] | barrier.
__device__ __forceinline__ void att_loop(
    const unsigned short* __restrict__ alphab, const unsigned short* __restrict__ x2T,
    int b, int i0, int d0, unsigned short* AS, f32x4 (&acc)[4][4])
{
  constexpr int HB = 128 * 32;   // u16 per buffer

  const int tid  = threadIdx.x;
  const int lane = tid & 63, wv = tid >> 6;
  const int wr = wv >> 1, wc = wv & 1;
  const int quad = lane >> 4, lx = lane & 15;
  const int lq  = lane >> 2;
  const int lsw = (lane & 3) ^ ((lane >> 3) & 3);

  unsigned short* a0 = AS;            unsigned short* b0 = AS + 3 * HB;
  unsigned short* a1 = AS + HB;       unsigned short* b1 = AS + 4 * HB;
  unsigned short* a2 = AS + 2 * HB;   unsigned short* b2 = AS + 5 * HB;

  const size_t abase = (size_t)(b * L_ + i0) * L_;
  const size_t bbase = ((size_t)(b * H_) + d0) * L_;

  // stage(tile jt) into (pa, pb): per wave 2 Aa + 2 Bt gld16 (queue order = read order)
#define ATT_STAGE(pa, pb, jt)                                                  \
  {                                                                            \
    const int j0s = (jt) * 32;                                                 \
    _Pragma("unroll")                                                          \
    for (int g = 0; g < 2; ++g) {                                              \
      const int rowl = wv * 32 + g * 16;                                       \
      gld16(alphab + abase + (size_t)(rowl + lq) * L_ + j0s + lsw * 8,         \
            (pa) + rowl * 32);                                                 \
    }                                                                          \
    _Pragma("unroll")                                                          \
    for (int g = 0; g < 2; ++g) {                                              \
      const int rowl = wv * 32 + g * 16;                                       \
      gld16(x2T + bbase + (size_t)(rowl + lq) * L_ + j0s + lsw * 8,            \
            (pb) + rowl * 32);                                                 \
    }                                                                          \
  }

  ATT_STAGE(a0, b0, 0)
  ATT_STAGE(a1, b1, 1)
  asm volatile("s_waitcnt vmcnt(4)" ::: "memory");   // tile 0 landed
  __builtin_amdgcn_s_barrier();

  for (int t = 0; t < 32; ++t) {
    bf16x8 fa[4], fb[4];
#pragma unroll
    for (int i = 0; i < 4; ++i) fa[i] = ld_frag_sw(a0, wr * 64 + i * 16 + lx, quad);
#pragma unroll
    for (int j = 0; j < 4; ++j) fb[j] = ld_frag_sw(b0, wc * 64 + j * 16 + lx, quad);
    if (t + 2 < 32) ATT_STAGE(a2, b2, t + 2)
    __builtin_amdgcn_s_setprio(1);
#pragma unroll
    for (int i = 0; i < 4; ++i)
#pragma unroll
      for (int j = 0; j < 4; ++j) acc[i][j] = MFMA(fa[i], fb[j], acc[i][j]);
    __builtin_amdgcn_s_setprio(0);
    if (t + 2 < 32)      asm volatile("s_waitcnt vmcnt(4)" ::: "memory");
    else if (t == 30)    asm volatile("s_waitcnt vmcnt(0)" ::: "memory");
    if (t < 31) __builtin_amdgcn_s_barrier();
    unsigned short* ta = a0; a0 = a1; a1 = a2; a2 = ta;
    unsigned short* tb = b0; b0 = b1; b1 = b2; b2 = tb;
  }
#undef ATT_STAGE
}

// ---------------- K4a: att = alpha @ x2 (store att fp32; fallback path) ---------
__global__ __launch_bounds__(256) void k_att(
    const unsigned short* __restrict__ alphab, const unsigned short* __restrict__ x2T,
    float* __restrict__ att)
{
  __shared__ unsigned short AS[6 * 128 * 32];   // 48 KB

  const int tid  = threadIdx.x;
  const int lane = tid & 63, wv = tid >> 6;
  const int wr = wv >> 1, wc = wv & 1;
  const int quad = lane >> 4, lx = lane & 15;
  (void)wv;

  const int lin = blockIdx.x;
  const int s   = (lin & 7) * 96 + (lin >> 3);
  const int d0  = (s % 6) * 128;
  const int i0  = ((s / 6) & 7) * 128;
  const int b   = s / 48;

  f32x4 acc[4][4] = {};
  att_loop(alphab, x2T, b, i0, d0, AS, acc);

#pragma unroll
  for (int j = 0; j < 4; ++j) {
    const int dd = d0 + wc * 64 + j * 16 + lx;
#pragma unroll
    for (int i = 0; i < 4; ++i) {
      const int ib = i0 + wr * 64 + i * 16 + quad * 4;
#pragma unroll
      for (int r = 0; r < 4; ++r)
        att[((size_t)(b * L_) + ib + r) * H_ + dd] = acc[i][j][r];
    }
  }
}

// ---------------- K4b: fused att + concat (requires alpha,x2T in d_ws) ----------
__global__ __launch_bounds__(256) void k_attcat(
    const unsigned short* __restrict__ alphab, const unsigned short* __restrict__ x2T,
    const float* __restrict__ x1, float* __restrict__ out)
{
  __shared__ unsigned short AS[6 * 128 * 32];   // 48 KB

  const int tid  = threadIdx.x;
  const int lane = tid & 63, wv = tid >> 6;
  const int wr = wv >> 1, wc = wv & 1;
  const int quad = lane >> 4, lx = lane & 15;
  (void)wv;

  const int lin = blockIdx.x;
  const int s   = (lin & 7) * 96 + (lin >> 3);
  const int d0  = (s % 6) * 128;
  const int i0  = ((s / 6) & 7) * 128;
  const int b   = s / 48;

  f32x4 acc[4][4] = {};
  att_loop(alphab, x2T, b, i0, d0, AS, acc);

#pragma unroll
  for (int j = 0; j < 4; ++j) {
    const int dd = d0 + wc * 64 + j * 16 + lx;
#pragma unroll
    for (int i = 0; i < 4; ++i) {
      const int ib = i0 + wr * 64 + i * 16 + quad * 4;
#pragma unroll
      for (int r = 0; r < 4; ++r) {
        const size_t row = (size_t)(b * L_) + ib + r;
        const float xv = x1[row * H_ + dd];
        const float av = acc[i][j][r];
        float* ob = out + row * (4 * H_) + dd;
        ob[0]      = xv;
        ob[H_]     = av;
        ob[2 * H_] = xv * av;
        ob[3 * H_] = xv - av;
      }
    }
  }
}

// ---------------- K5: out = [x1, att, x1*att, x1-att] (fallback path) -----------
__global__ __launch_bounds__(256) void k_concat(
    const float* __restrict__ x1, const float* __restrict__ att,
    float* __restrict__ out)
{
  const int gid = blockIdx.x * 256 + threadIdx.x;
  const int row = gid / 192;
  const int c   = (gid % 192) * 4;

  f32x4 xv = *(const f32x4*)(x1  + (size_t)row * H_ + c);
  f32x4 av = *(const f32x4*)(att + (size_t)row * H_ + c);
  f32x4 mv, sv;
#pragma unroll
  for (int q = 0; q < 4; ++q) { mv[q] = xv[q] * av[q]; sv[q] = xv[q] - av[q]; }

  float* ob = out + (size_t)row * (4 * H_) + c;
  *(f32x4*)(ob)          = xv;
  *(f32x4*)(ob + H_)     = av;
  *(f32x4*)(ob + 2 * H_) = mv;
  *(f32x4*)(ob + 3 * H_) = sv;
}

extern "C" void kernel_launch(void* const* d_in, const int* in_sizes, int n_in,
                              void* d_out, int out_size, void* d_ws, size_t ws_size,
                              hipStream_t stream) {
  const float* x1      = (const float*)d_in[0];
  const float* x2      = (const float*)d_in[1];
  // d_in[2] = x1_mask : unused
  const int*   x2_mask = (const int*)d_in[3];
  const float* W       = (const float*)d_in[4];
  const float* bias    = (const float*)d_in[5];
  float* out = (float*)d_out;

  char* o8 = (char*)d_out;
  char* w8 = (char*)d_ws;
  unsigned short* Ph     = (unsigned short*)o8;                          // [0, 50331648)
  unsigned short* Pl     = (unsigned short*)(o8 + 50331648);             // [.., 100663296)
  float*          scores = (float*)(o8 + 100663296);                     // [.., 167772160)
  unsigned short* Xh     = (unsigned short*)(o8 + 100663296);            // alias (early)
  unsigned short* Wh     = (unsigned short*)(o8 + 167772160);            // 1.18 MB
  unsigned short* Wl     = (unsigned short*)(o8 + 168951808);            // 1.18 MB
  unsigned short* Xl     = (unsigned short*)d_ws;                        // [0, 50331648)

  // fused path needs Xl(50.3M)+x2T(25.2M) in ws simultaneously, alpha reuses
  // ws[0,33.5M) after Xl dies.
  const bool fused = (ws_size >= (size_t)75497472);
  unsigned short* x2T    = fused ? (unsigned short*)(w8 + 50331648)
                                 : (unsigned short*)(o8 + 170131456);
  unsigned short* alphab = fused ? (unsigned short*)w8
                                 : (unsigned short*)o8;                  // alias Ph (late)
  float*          att    = (float*)d_ws;                                 // alias Xl (late)

  k_split  <<<dim3(XB_ + WB_ + TB_), 256, 0, stream>>>(x1, x2, W, Xh, Xl, Wh, Wl, x2T);
  k_proj   <<<dim3(768),   512, 0, stream>>>(Xh, Xl, Wh, Wl, bias, Ph, Pl);
  k_scores <<<dim3(256),   512, 0, stream>>>(Ph, Pl, x2_mask, scores);
  k_softmax<<<dim3(16384), 256, 0, stream>>>(scores, alphab);
  if (fused) {
    k_attcat<<<dim3(768),  256, 0, stream>>>(alphab, x2T, x1, out);
  } else {
    k_att   <<<dim3(768),  256, 0, stream>>>(alphab, x2T, att);
    k_concat<<<dim3(12288), 256, 0, stream>>>(x1, att, out);
  }
}

// Round 4
// 580.885 us; speedup vs baseline: 1.1086x; 1.0103x over previous
//
#include <hip/hip_runtime.h>

// B=16, L1=L2=1024, H=768
// P = relu([x1;x2] @ W^T + b); S = P1·P2^T masked; softmax; att = alpha·x2;
// out = [x1, att, x1*att, x1-att]
//
// Numerics identical to the previous passing versions (hi/lo split-bf16 3-pass
// MFMA for proj+scores, order hh,hl,lh per 32-wide K-step; single-pass bf16 att).
//
// Round-4 changes (k_proj/k_scores only):
//  - re-tiled 128x128, 4 waves (256 thr), per-wave 64x64; LDS 64 KB ->
//    2 independent blocks/CU. Round-3 counters showed latency-bound convoy
//    (MfmaUtil 34.6 / VALU 18 / HBM 22 -- nothing saturated) with 1 block/CU:
//    every counted wait stalled the whole CU. Second resident block provides
//    the wave-level overlap (m114) during vmcnt/barrier stalls.
//  - same 2-phase schedule + counted vmcnt(4) (CA=2), same queue order
//    [Ah,Bh | Bl,Al] == read order; sync skeleton unchanged from the
//    verified round-3 loop.
//  - k_proj epilogue store order i,r-outer / j-inner for L2 line merging
//    (WRITE_SIZE was 1.68x ideal).
//
// d_out layout (lifetimes), non-fused path:
//   [0,50.3M)        Ph (proj->scores), then alpha_bf16 [0,33.5M) (softmax->att)
//   [50.3M,100.7M)   Pl
//   [100.7M,167.8M)  Xh (split->proj), then scores fp32 (scores->softmax)
//   [167.8M,169.0M)  Wh   [169.0M,170.1M) Wl   [170.1M,195.3M) x2T bf16
// d_ws: [0,50.3M) Xl (split->proj), then att fp32 (att->concat)
//
// fused path: alpha -> d_ws[0,33.5M) (after Xl dies), x2T -> d_ws[50.3M,75.5M),
// out written over all of d_out by k_attcat.

#define B_  16
#define L_  1024
#define H_  768
#define M1_ (B_ * L_)    // 16384
#define MT_ (2 * M1_)    // 32768

#define XB_  24576       // k_split blocks for X hi/lo
#define WB_  576         // k_split blocks for W hi/lo
#define TB_  3072        // k_split blocks for x2 transpose

using f32x4  = __attribute__((ext_vector_type(4))) float;
using bf16x8 = __attribute__((ext_vector_type(8))) __bf16;
using u16x8  = __attribute__((ext_vector_type(8))) unsigned short;
using u16x4  = __attribute__((ext_vector_type(4))) unsigned short;

__device__ inline unsigned short f2b(float f) {
  unsigned u = __builtin_bit_cast(unsigned, f);
  u += 0x7FFFu + ((u >> 16) & 1u);   // RNE; no NaN/inf in data
  return (unsigned short)(u >> 16);
}
__device__ inline float b2f(unsigned short u) {
  return __builtin_bit_cast(float, ((unsigned)u) << 16);
}

// async global->LDS, 16 B per lane; LDS dest = wave-uniform base + lane*16
__device__ inline void gld16(const void* g, void* l) {
  __builtin_amdgcn_global_load_lds(
      (__attribute__((address_space(1))) void*)g,
      (__attribute__((address_space(3))) void*)l, 16, 0, 0);
}

// Tile: [rows][32 u16] = 64 B/row, chunk (16B) swizzle: slot = chunk ^ ((row>>1)&3).
// ds_read_b128 fragment reads measured conflict-free (SQ_LDS_BANK_CONFLICT = 0).
__device__ inline bf16x8 ld_frag_sw(const unsigned short* lds, int row, int quad) {
  const int sl = quad ^ ((row >> 1) & 3);
  u16x8 v = *(const u16x8*)(lds + row * 32 + sl * 8);
  return __builtin_bit_cast(bf16x8, v);
}

#define MFMA(a, b, c) __builtin_amdgcn_mfma_f32_16x16x32_bf16((a), (b), (c), 0, 0, 0)

// Stage one 128x32-u16 matrix-half (8 KB) with 4 waves: 2 gld16 per wave.
// Source chunk pre-swizzled (lsw) so linear LDS writes realize the read swizzle.
__device__ __forceinline__ void stage128(const unsigned short* __restrict__ src,
                                         unsigned short* ldsbase,
                                         int wv, int lq, int lsw,
                                         size_t row0, int k0) {
#pragma unroll
  for (int g = 0; g < 2; ++g) {
    const int rowl = wv * 32 + g * 16;
    gld16(src + (row0 + rowl + lq) * (size_t)H_ + k0 + lsw * 8,
          ldsbase + rowl * 32);
  }
}

// 128x128 tile, BK=32, hi/lo 3-pass K-loop. 4 waves (2Mx2N), per-wave 64x64.
// Double-buffered LDS (64 KB -> 2 blocks/CU), 2-phase schedule:
//   ph0: ds_read fah,fbh | issue Ah,Bh(t+1) | MFMA hh        | vmcnt(4) | bar
//   ph1: ds_read fbl | issue Bl(t+1) | MFMA hl |
//        ds_read fal | issue Al(t+1) | MFMA lh | vmcnt(4) | bar
// Per-wave load queue is always [Ah(2),Bh(2),Bl(2),Al(2)] in read order; each
// wait retires exactly the group the next phase reads; 8 deep max, >= 4 always
// in flight. Last step: ph0 waits vmcnt(0), ph1 waits nothing.
__device__ __forceinline__ void gemm3_loop4(
    const unsigned short* __restrict__ Agh, const unsigned short* __restrict__ Agl,
    const unsigned short* __restrict__ Bgh, const unsigned short* __restrict__ Bgl,
    size_t arow0, size_t brow0,
    unsigned short* SA, unsigned short* SB, f32x4 (&acc)[4][4])
{
  constexpr int HB = 128 * 32;   // u16 per half-buffer (8 KB)

  const int tid  = threadIdx.x;
  const int lane = tid & 63, wv = tid >> 6;
  const int wr = wv >> 1, wc = wv & 1;
  const int quad = lane >> 4, lx = lane & 15;
  const int lq  = lane >> 2;
  const int lsw = (lane & 3) ^ ((lane >> 3) & 3);

  // prologue: tile 0 -> buf 0; queue [Ah(2), Bh(2), Bl(2), Al(2)]
  stage128(Agh, SA,      wv, lq, lsw, arow0, 0);
  stage128(Bgh, SB,      wv, lq, lsw, brow0, 0);
  stage128(Bgl, SB + HB, wv, lq, lsw, brow0, 0);
  stage128(Agl, SA + HB, wv, lq, lsw, arow0, 0);
  asm volatile("s_waitcnt vmcnt(4)" ::: "memory");   // Ah0,Bh0 landed
  __builtin_amdgcn_s_barrier();

  int c = 0;
  for (int t = 0; t < H_ / 32; ++t) {
    unsigned short* sAh = SA + c * (2 * HB);
    unsigned short* sAl = sAh + HB;
    unsigned short* sBh = SB + c * (2 * HB);
    unsigned short* sBl = sBh + HB;
    unsigned short* dA  = SA + (c ^ 1) * (2 * HB);
    unsigned short* dB  = SB + (c ^ 1) * (2 * HB);
    const int  k1   = t * 32 + 32;
    const bool more = (t < H_ / 32 - 1);

    // ---------------- phase 0 : hh ----------------
    bf16x8 fah[4], fbh[4];
#pragma unroll
    for (int i = 0; i < 4; ++i)
      fah[i] = ld_frag_sw(sAh, wr * 64 + i * 16 + lx, quad);
#pragma unroll
    for (int j = 0; j < 4; ++j)
      fbh[j] = ld_frag_sw(sBh, wc * 64 + j * 16 + lx, quad);
    if (more) {
      stage128(Agh, dA, wv, lq, lsw, arow0, k1);
      stage128(Bgh, dB, wv, lq, lsw, brow0, k1);
    }
    __builtin_amdgcn_s_setprio(1);
#pragma unroll
    for (int i = 0; i < 4; ++i)
#pragma unroll
      for (int j = 0; j < 4; ++j) acc[i][j] = MFMA(fah[i], fbh[j], acc[i][j]);
    __builtin_amdgcn_s_setprio(0);
    if (more) asm volatile("s_waitcnt vmcnt(4)" ::: "memory");
    else      asm volatile("s_waitcnt vmcnt(0)" ::: "memory");
    __builtin_amdgcn_s_barrier();

    // ---------------- phase 1 : hl + lh ----------------
    bf16x8 fbl[4];
#pragma unroll
    for (int j = 0; j < 4; ++j)
      fbl[j] = ld_frag_sw(sBl, wc * 64 + j * 16 + lx, quad);
    if (more) stage128(Bgl, dB + HB, wv, lq, lsw, brow0, k1);
    __builtin_amdgcn_s_setprio(1);
#pragma unroll
    for (int i = 0; i < 4; ++i)
#pragma unroll
      for (int j = 0; j < 4; ++j) acc[i][j] = MFMA(fah[i], fbl[j], acc[i][j]);
    __builtin_amdgcn_s_setprio(0);

    bf16x8 fal[4];
#pragma unroll
    for (int i = 0; i < 4; ++i)
      fal[i] = ld_frag_sw(sAl, wr * 64 + i * 16 + lx, quad);
    if (more) stage128(Agl, dA + HB, wv, lq, lsw, arow0, k1);
    __builtin_amdgcn_s_setprio(1);
#pragma unroll
    for (int i = 0; i < 4; ++i)
#pragma unroll
      for (int j = 0; j < 4; ++j) acc[i][j] = MFMA(fal[i], fbh[j], acc[i][j]);
    __builtin_amdgcn_s_setprio(0);
    if (more) {
      asm volatile("s_waitcnt vmcnt(4)" ::: "memory");
      __builtin_amdgcn_s_barrier();
    }
    c ^= 1;
  }
}

// ---------------- K0: split X,W into hi/lo bf16; build x2T bf16 -----------------
__global__ __launch_bounds__(256) void k_split(
    const float* __restrict__ x1, const float* __restrict__ x2,
    const float* __restrict__ W,
    unsigned short* __restrict__ Xh, unsigned short* __restrict__ Xl,
    unsigned short* __restrict__ Wh, unsigned short* __restrict__ Wl,
    unsigned short* __restrict__ x2T)
{
  __shared__ unsigned short tile[64][72];
  const int tid = threadIdx.x;
  const int bx  = blockIdx.x;

  if (bx < XB_) {
    const size_t idx = (size_t)bx * 256 + tid;          // f32x4 index over [32768][768]
    const int row = (int)(idx / 192);
    const int col = ((int)(idx % 192)) * 4;
    const float* src = (row < M1_) ? (x1 + (size_t)row * H_ + col)
                                   : (x2 + (size_t)(row - M1_) * H_ + col);
    f32x4 v = *(const f32x4*)src;
    u16x4 h, l;
#pragma unroll
    for (int q = 0; q < 4; ++q) { h[q] = f2b(v[q]); l[q] = f2b(v[q] - b2f(h[q])); }
    *(u16x4*)(Xh + idx * 4) = h;
    *(u16x4*)(Xl + idx * 4) = l;
  } else if (bx < XB_ + WB_) {
    const int idx = (bx - XB_) * 256 + tid;
    f32x4 v = *(const f32x4*)(W + (size_t)idx * 4);
    u16x4 h, l;
#pragma unroll
    for (int q = 0; q < 4; ++q) { h[q] = f2b(v[q]); l[q] = f2b(v[q] - b2f(h[q])); }
    *(u16x4*)(Wh + (size_t)idx * 4) = h;
    *(u16x4*)(Wl + (size_t)idx * 4) = l;
  } else {
    const int t  = bx - (XB_ + WB_);
    const int b  = t / 192;
    const int r  = t % 192;
    const int j0 = (r / 12) * 64;
    const int d0 = (r % 12) * 64;
#pragma unroll
    for (int p = 0; p < 4; ++p) {
      const int idx = tid + p * 256;
      const int jr  = idx >> 4;
      const int dc  = (idx & 15) * 4;
      f32x4 v = *(const f32x4*)(x2 + ((size_t)(b * L_ + j0 + jr)) * H_ + d0 + dc);
#pragma unroll
      for (int q = 0; q < 4; ++q) tile[jr][dc + q] = f2b(v[q]);
    }
    __syncthreads();
#pragma unroll
    for (int p = 0; p < 2; ++p) {
      const int idx = tid + p * 256;
      const int dr  = idx >> 3;
      const int jc  = (idx & 7) * 8;
      u16x8 o;
#pragma unroll
      for (int q = 0; q < 8; ++q) o[q] = tile[jc + q][dr];
      *(u16x8*)(x2T + ((size_t)(b * H_) + d0 + dr) * L_ + j0 + jc) = o;
    }
  }
}

// ---------------- K1: P = relu(X @ W^T + b), 3-pass hi/lo, store Ph/Pl ----------
// 128x128 tile -> 256x6 = 1536 blocks, 2 blocks/CU -> exactly 3 full rounds.
__global__ __launch_bounds__(256, 2) void k_proj(
    const unsigned short* __restrict__ Xh, const unsigned short* __restrict__ Xl,
    const unsigned short* __restrict__ Wh, const unsigned short* __restrict__ Wl,
    const float* __restrict__ bias,
    unsigned short* __restrict__ Ph, unsigned short* __restrict__ Pl)
{
  __shared__ unsigned short SA[2 * 2 * 128 * 32];   // 32 KB
  __shared__ unsigned short SB[2 * 2 * 128 * 32];   // 32 KB

  const int tid  = threadIdx.x;
  const int lane = tid & 63, wv = tid >> 6;
  const int wr = wv >> 1, wc = wv & 1;
  const int quad = lane >> 4, lx = lane & 15;

  // XCD-chunked bijective swizzle: 1536 blocks, 192/XCD; n fastest within an
  // m-panel -> the X 128-row panel is read 6x from the same XCD's L2.
  const int lin = blockIdx.x;
  const int s   = (lin & 7) * 192 + (lin >> 3);
  const int n0  = (s % 6) * 128;
  const int m0  = (s / 6) * 128;

  f32x4 acc[4][4] = {};
  gemm3_loop4(Xh, Xl, Wh, Wl, (size_t)m0, (size_t)n0, SA, SB, acc);

  float bv[4];
#pragma unroll
  for (int j = 0; j < 4; ++j) bv[j] = bias[n0 + wc * 64 + j * 16 + lx];

#pragma unroll
  for (int i = 0; i < 4; ++i) {
#pragma unroll
    for (int r = 0; r < 4; ++r) {
      const size_t rowoff = (size_t)(m0 + wr * 64 + i * 16 + quad * 4 + r) * H_;
#pragma unroll
      for (int j = 0; j < 4; ++j) {
        float v = acc[i][j][r] + bv[j];
        v = v > 0.f ? v : 0.f;
        const unsigned short hh = f2b(v);
        const unsigned short ll = f2b(v - b2f(hh));
        const size_t off = rowoff + n0 + wc * 64 + j * 16 + lx;
        Ph[off] = hh;
        Pl[off] = ll;
      }
    }
  }
}

// ---------------- K2: scores = P1·P2^T (3-pass), masked -------------------------
// 128x128 tile -> 8x8x16 = 1024 blocks, 2 blocks/CU -> exactly 2 full rounds.
__global__ __launch_bounds__(256, 2) void k_scores(
    const unsigned short* __restrict__ Ph, const unsigned short* __restrict__ Pl,
    const int* __restrict__ x2_mask, float* __restrict__ scores)
{
  __shared__ unsigned short SA[2 * 2 * 128 * 32];   // 32 KB
  __shared__ unsigned short SB[2 * 2 * 128 * 32];   // 32 KB

  const int tid  = threadIdx.x;
  const int lane = tid & 63, wv = tid >> 6;
  const int wr = wv >> 1, wc = wv & 1;
  const int quad = lane >> 4, lx = lane & 15;

  // 1024 blocks, 128/XCD; j fastest -> i-panel read 8x from the same XCD's L2.
  const int lin = blockIdx.x;
  const int s   = (lin & 7) * 128 + (lin >> 3);
  const int j0  = (s & 7) * 128;
  const int i0  = ((s >> 3) & 7) * 128;
  const int b   = s >> 6;

  f32x4 acc[4][4] = {};
  gemm3_loop4(Ph, Pl, Ph, Pl,
              (size_t)(b * L_ + i0), (size_t)(M1_ + b * L_ + j0), SA, SB, acc);

#pragma unroll
  for (int j = 0; j < 4; ++j) {
    const int jj = j0 + wc * 64 + j * 16 + lx;
    const int mv = x2_mask[b * L_ + jj];
#pragma unroll
    for (int i = 0; i < 4; ++i) {
      const int ib = i0 + wr * 64 + i * 16 + quad * 4;
#pragma unroll
      for (int r = 0; r < 4; ++r) {
        const float v = mv ? -1e30f : acc[i][j][r];
        scores[((size_t)(b * L_) + ib + r) * L_ + jj] = v;
      }
    }
  }
}

// ---------------- K3: row softmax, fp32 in -> bf16 alpha out --------------------
__global__ __launch_bounds__(256) void k_softmax(
    const float* __restrict__ scores, unsigned short* __restrict__ alphab)
{
  const size_t row = blockIdx.x;
  const float* p = scores + row * L_;
  const int tid = threadIdx.x;

  f32x4 v = *(const f32x4*)(p + tid * 4);
  float m = fmaxf(fmaxf(v[0], v[1]), fmaxf(v[2], v[3]));
#pragma unroll
  for (int off = 32; off > 0; off >>= 1) m = fmaxf(m, __shfl_down(m, off));

  __shared__ float rmax[4];
  __shared__ float rsum[4];
  const int wid = tid >> 6, lane = tid & 63;
  if (lane == 0) rmax[wid] = m;
  __syncthreads();
  m = fmaxf(fmaxf(rmax[0], rmax[1]), fmaxf(rmax[2], rmax[3]));

  f32x4 e;
#pragma unroll
  for (int q = 0; q < 4; ++q) e[q] = __expf(v[q] - m);
  float s = e[0] + e[1] + e[2] + e[3];
#pragma unroll
  for (int off = 32; off > 0; off >>= 1) s += __shfl_down(s, off);
  if (lane == 0) rsum[wid] = s;
  __syncthreads();
  s = rsum[0] + rsum[1] + rsum[2] + rsum[3];

  const float inv = 1.0f / s;
  u16x4 o;
#pragma unroll
  for (int q = 0; q < 4; ++q) o[q] = f2b(e[q] * inv);
  *(u16x4*)(alphab + row * L_ + tid * 4) = o;
}

// ------- att GEMM inner loop: triple-buffered, counted vmcnt, 1 barrier/step ----
// 4 waves (2x2), per-wave 64x64 out; LDS 3 x (Aa 8KB + Bt 8KB) = 48 KB.
// Per step: read fa,fb from buf t%3 | stage j0=(t+2)*32 into buf (t+2)%3 |
// 16 MFMA | vmcnt(4) [retires step t+1's 4 loads] | barrier.
__device__ __forceinline__ void att_loop(
    const unsigned short* __restrict__ alphab, const unsigned short* __restrict__ x2T,
    int b, int i0, int d0, unsigned short* AS, f32x4 (&acc)[4][4])
{
  constexpr int HB = 128 * 32;   // u16 per buffer

  const int tid  = threadIdx.x;
  const int lane = tid & 63, wv = tid >> 6;
  const int wr = wv >> 1, wc = wv & 1;
  const int quad = lane >> 4, lx = lane & 15;
  const int lq  = lane >> 2;
  const int lsw = (lane & 3) ^ ((lane >> 3) & 3);

  unsigned short* a0 = AS;            unsigned short* b0 = AS + 3 * HB;
  unsigned short* a1 = AS + HB;       unsigned short* b1 = AS + 4 * HB;
  unsigned short* a2 = AS + 2 * HB;   unsigned short* b2 = AS + 5 * HB;

  const size_t abase = (size_t)(b * L_ + i0) * L_;
  const size_t bbase = ((size_t)(b * H_) + d0) * L_;

  // stage(tile jt) into (pa, pb): per wave 2 Aa + 2 Bt gld16 (queue order = read order)
#define ATT_STAGE(pa, pb, jt)                                                  \
  {                                                                            \
    const int j0s = (jt) * 32;                                                 \
    _Pragma("unroll")                                                          \
    for (int g = 0; g < 2; ++g) {                                              \
      const int rowl = wv * 32 + g * 16;                                       \
      gld16(alphab + abase + (size_t)(rowl + lq) * L_ + j0s + lsw * 8,         \
            (pa) + rowl * 32);                                                 \
    }                                                                          \
    _Pragma("unroll")                                                          \
    for (int g = 0; g < 2; ++g) {                                              \
      const int rowl = wv * 32 + g * 16;                                       \
      gld16(x2T + bbase + (size_t)(rowl + lq) * L_ + j0s + lsw * 8,            \
            (pb) + rowl * 32);                                                 \
    }                                                                          \
  }

  ATT_STAGE(a0, b0, 0)
  ATT_STAGE(a1, b1, 1)
  asm volatile("s_waitcnt vmcnt(4)" ::: "memory");   // tile 0 landed
  __builtin_amdgcn_s_barrier();

  for (int t = 0; t < 32; ++t) {
    bf16x8 fa[4], fb[4];
#pragma unroll
    for (int i = 0; i < 4; ++i) fa[i] = ld_frag_sw(a0, wr * 64 + i * 16 + lx, quad);
#pragma unroll
    for (int j = 0; j < 4; ++j) fb[j] = ld_frag_sw(b0, wc * 64 + j * 16 + lx, quad);
    if (t + 2 < 32) ATT_STAGE(a2, b2, t + 2)
    __builtin_amdgcn_s_setprio(1);
#pragma unroll
    for (int i = 0; i < 4; ++i)
#pragma unroll
      for (int j = 0; j < 4; ++j) acc[i][j] = MFMA(fa[i], fb[j], acc[i][j]);
    __builtin_amdgcn_s_setprio(0);
    if (t + 2 < 32)      asm volatile("s_waitcnt vmcnt(4)" ::: "memory");
    else if (t == 30)    asm volatile("s_waitcnt vmcnt(0)" ::: "memory");
    if (t < 31) __builtin_amdgcn_s_barrier();
    unsigned short* ta = a0; a0 = a1; a1 = a2; a2 = ta;
    unsigned short* tb = b0; b0 = b1; b1 = b2; b2 = tb;
  }
#undef ATT_STAGE
}

// ---------------- K4a: att = alpha @ x2 (store att fp32; fallback path) ---------
__global__ __launch_bounds__(256) void k_att(
    const unsigned short* __restrict__ alphab, const unsigned short* __restrict__ x2T,
    float* __restrict__ att)
{
  __shared__ unsigned short AS[6 * 128 * 32];   // 48 KB

  const int tid  = threadIdx.x;
  const int lane = tid & 63, wv = tid >> 6;
  const int wr = wv >> 1, wc = wv & 1;
  const int quad = lane >> 4, lx = lane & 15;
  (void)wv;

  const int lin = blockIdx.x;
  const int s   = (lin & 7) * 96 + (lin >> 3);
  const int d0  = (s % 6) * 128;
  const int i0  = ((s / 6) & 7) * 128;
  const int b   = s / 48;

  f32x4 acc[4][4] = {};
  att_loop(alphab, x2T, b, i0, d0, AS, acc);

#pragma unroll
  for (int j = 0; j < 4; ++j) {
    const int dd = d0 + wc * 64 + j * 16 + lx;
#pragma unroll
    for (int i = 0; i < 4; ++i) {
      const int ib = i0 + wr * 64 + i * 16 + quad * 4;
#pragma unroll
      for (int r = 0; r < 4; ++r)
        att[((size_t)(b * L_) + ib + r) * H_ + dd] = acc[i][j][r];
    }
  }
}

// ---------------- K4b: fused att + concat (requires alpha,x2T in d_ws) ----------
__global__ __launch_bounds__(256) void k_attcat(
    const unsigned short* __restrict__ alphab, const unsigned short* __restrict__ x2T,
    const float* __restrict__ x1, float* __restrict__ out)
{
  __shared__ unsigned short AS[6 * 128 * 32];   // 48 KB

  const int tid  = threadIdx.x;
  const int lane = tid & 63, wv = tid >> 6;
  const int wr = wv >> 1, wc = wv & 1;
  const int quad = lane >> 4, lx = lane & 15;
  (void)wv;

  const int lin = blockIdx.x;
  const int s   = (lin & 7) * 96 + (lin >> 3);
  const int d0  = (s % 6) * 128;
  const int i0  = ((s / 6) & 7) * 128;
  const int b   = s / 48;

  f32x4 acc[4][4] = {};
  att_loop(alphab, x2T, b, i0, d0, AS, acc);

#pragma unroll
  for (int j = 0; j < 4; ++j) {
    const int dd = d0 + wc * 64 + j * 16 + lx;
#pragma unroll
    for (int i = 0; i < 4; ++i) {
      const int ib = i0 + wr * 64 + i * 16 + quad * 4;
#pragma unroll
      for (int r = 0; r < 4; ++r) {
        const size_t row = (size_t)(b * L_) + ib + r;
        const float xv = x1[row * H_ + dd];
        const float av = acc[i][j][r];
        float* ob = out + row * (4 * H_) + dd;
        ob[0]      = xv;
        ob[H_]     = av;
        ob[2 * H_] = xv * av;
        ob[3 * H_] = xv - av;
      }
    }
  }
}

// ---------------- K5: out = [x1, att, x1*att, x1-att] (fallback path) -----------
__global__ __launch_bounds__(256) void k_concat(
    const float* __restrict__ x1, const float* __restrict__ att,
    float* __restrict__ out)
{
  const int gid = blockIdx.x * 256 + threadIdx.x;
  const int row = gid / 192;
  const int c   = (gid % 192) * 4;

  f32x4 xv = *(const f32x4*)(x1  + (size_t)row * H_ + c);
  f32x4 av = *(const f32x4*)(att + (size_t)row * H_ + c);
  f32x4 mv, sv;
#pragma unroll
  for (int q = 0; q < 4; ++q) { mv[q] = xv[q] * av[q]; sv[q] = xv[q] - av[q]; }

  float* ob = out + (size_t)row * (4 * H_) + c;
  *(f32x4*)(ob)          = xv;
  *(f32x4*)(ob + H_)     = av;
  *(f32x4*)(ob + 2 * H_) = mv;
  *(f32x4*)(ob + 3 * H_) = sv;
}

extern "C" void kernel_launch(void* const* d_in, const int* in_sizes, int n_in,
                              void* d_out, int out_size, void* d_ws, size_t ws_size,
                              hipStream_t stream) {
  const float* x1      = (const float*)d_in[0];
  const float* x2      = (const float*)d_in[1];
  // d_in[2] = x1_mask : unused
  const int*   x2_mask = (const int*)d_in[3];
  const float* W       = (const float*)d_in[4];
  const float* bias    = (const float*)d_in[5];
  float* out = (float*)d_out;

  char* o8 = (char*)d_out;
  char* w8 = (char*)d_ws;
  unsigned short* Ph     = (unsigned short*)o8;                          // [0, 50331648)
  unsigned short* Pl     = (unsigned short*)(o8 + 50331648);             // [.., 100663296)
  float*          scores = (float*)(o8 + 100663296);                     // [.., 167772160)
  unsigned short* Xh     = (unsigned short*)(o8 + 100663296);            // alias (early)
  unsigned short* Wh     = (unsigned short*)(o8 + 167772160);            // 1.18 MB
  unsigned short* Wl     = (unsigned short*)(o8 + 168951808);            // 1.18 MB
  unsigned short* Xl     = (unsigned short*)d_ws;                        // [0, 50331648)

  // fused path needs Xl(50.3M)+x2T(25.2M) in ws simultaneously, alpha reuses
  // ws[0,33.5M) after Xl dies.
  const bool fused = (ws_size >= (size_t)75497472);
  unsigned short* x2T    = fused ? (unsigned short*)(w8 + 50331648)
                                 : (unsigned short*)(o8 + 170131456);
  unsigned short* alphab = fused ? (unsigned short*)w8
                                 : (unsigned short*)o8;                  // alias Ph (late)
  float*          att    = (float*)d_ws;                                 // alias Xl (late)

  k_split  <<<dim3(XB_ + WB_ + TB_), 256, 0, stream>>>(x1, x2, W, Xh, Xl, Wh, Wl, x2T);
  k_proj   <<<dim3(1536),  256, 0, stream>>>(Xh, Xl, Wh, Wl, bias, Ph, Pl);
  k_scores <<<dim3(1024),  256, 0, stream>>>(Ph, Pl, x2_mask, scores);
  k_softmax<<<dim3(16384), 256, 0, stream>>>(scores, alphab);
  if (fused) {
    k_attcat<<<dim3(768),  256, 0, stream>>>(alphab, x2T, x1, out);
  } else {
    k_att   <<<dim3(768),  256, 0, stream>>>(alphab, x2T, att);
    k_concat<<<dim3(12288), 256, 0, stream>>>(x1, att, out);
  }
}